// Round 1
// baseline (1142.844 us; speedup 1.0000x reference)
//
#include <hip/hip_runtime.h>

#define HD 128

// ---------------- CSR build ----------------

__global__ void k_deg(const int* __restrict__ dst, int* __restrict__ degi, int E) {
    int i = blockIdx.x * blockDim.x + threadIdx.x;
    int stride = gridDim.x * blockDim.x;
    for (int e = i; e < E; e += stride) atomicAdd(&degi[dst[e]], 1);
}

// block scans 1024 elements (256 threads x 4)
__global__ void k_scan1(const int* __restrict__ degi, int* __restrict__ rowptr,
                        int* __restrict__ bsum, int N) {
    __shared__ int lds[256];
    int tid = threadIdx.x;
    int base = blockIdx.x * 1024 + tid * 4;
    int v[4]; int s = 0;
#pragma unroll
    for (int j = 0; j < 4; ++j) { int idx = base + j; v[j] = (idx < N) ? degi[idx] : 0; s += v[j]; }
    lds[tid] = s; __syncthreads();
    for (int off = 1; off < 256; off <<= 1) {
        int t = 0;
        if (tid >= off) t = lds[tid - off];
        __syncthreads();
        if (tid >= off) lds[tid] += t;
        __syncthreads();
    }
    int excl = lds[tid] - s;
#pragma unroll
    for (int j = 0; j < 4; ++j) { int idx = base + j; if (idx < N) rowptr[idx] = excl; excl += v[j]; }
    if (tid == 255) bsum[blockIdx.x] = lds[255];
}

__global__ void k_scan2(const int* __restrict__ bsum, int* __restrict__ boffs, int nb) {
    if (threadIdx.x == 0 && blockIdx.x == 0) {
        int acc = 0;
        for (int i = 0; i < nb; ++i) { boffs[i] = acc; acc += bsum[i]; }
    }
}

__global__ void k_scan3(int* __restrict__ rowptr, const int* __restrict__ boffs, int N, int E) {
    int i = blockIdx.x * blockDim.x + threadIdx.x;
    int stride = gridDim.x * blockDim.x;
    for (int idx = i; idx < N; idx += stride) rowptr[idx] += boffs[idx >> 10];
    if (i == 0) rowptr[N] = E;
}

__global__ void k_inv(const int* __restrict__ degi, float* __restrict__ inv, int N) {
    int i = blockIdx.x * blockDim.x + threadIdx.x;
    int stride = gridDim.x * blockDim.x;
    for (int n = i; n < N; n += stride) inv[n] = (degi[n] > 0) ? (1.0f / (float)degi[n]) : 0.0f;
}

__global__ void k_fill(const int* __restrict__ src, const int* __restrict__ dst,
                       const int* __restrict__ rowptr, int* __restrict__ cursor,
                       int* __restrict__ csr, int E) {
    int i = blockIdx.x * blockDim.x + threadIdx.x;
    int stride = gridDim.x * blockDim.x;
    for (int e = i; e < E; e += stride) {
        int d = dst[e];
        int pos = atomicAdd(&cursor[d], 1);
        csr[rowptr[d] + pos] = src[e];
    }
}

// ---------------- Aggregation: agg[n] = mean_{s in N(n)} h[s] ----------------
// one block (128 threads) per node; coalesced 512B row gathers
__global__ void k_agg(const float* __restrict__ h, const int* __restrict__ rowptr,
                      const int* __restrict__ csr, const float* __restrict__ inv,
                      float* __restrict__ agg, int N) {
    int n = blockIdx.x;
    if (n >= N) return;
    int c = threadIdx.x;
    int beg = rowptr[n], end = rowptr[n + 1];
    float acc = 0.0f;
    for (int k = beg; k < end; ++k) {
        int s = csr[k];
        acc += h[s * HD + c];
    }
    agg[n * HD + c] = acc * inv[n];
}

// ---------------- Fused dual GEMM + bias + column-stats ----------------
// out = X1 @ W1 + bias + X2 @ W2 ;  stats[copy][0:128]=colsum, [128:256]=colsumsq
// block: 256 threads, 64 rows x 128 cols, K=256 in 4 chunks of 64
#define NCOPY 32
__global__ __launch_bounds__(256) void k_gemm(
        const float* __restrict__ X1, const float* __restrict__ X2,
        const float* __restrict__ W1, const float* __restrict__ W2,
        const float* __restrict__ bias, float* __restrict__ out,
        float* __restrict__ stats, int N) {
    __shared__ float Xs[64][64];   // 16KB
    __shared__ float Ws[64][128];  // 32KB
    int tid = threadIdx.x;
    int tx = tid & 31;       // col group: cols tx*4 .. tx*4+3
    int ty = tid >> 5;       // row group: rows ty*8 .. ty*8+7
    int rbase = blockIdx.x * 64;

    float4 acc[8];
#pragma unroll
    for (int i = 0; i < 8; ++i) acc[i] = make_float4(0.f, 0.f, 0.f, 0.f);

    for (int ch = 0; ch < 4; ++ch) {
        const float* X = (ch < 2) ? X1 : X2;
        const float* W = (ch < 2) ? W1 : W2;
        int k0 = (ch & 1) * 64;
        // stage X tile [64 rows][64 k]
        {
            int kq = (tid & 15) * 4;
            int r0 = tid >> 4;  // 0..15
#pragma unroll
            for (int p = 0; p < 4; ++p) {
                int r = r0 + p * 16;
                int row = rbase + r;
                float4 v = make_float4(0.f, 0.f, 0.f, 0.f);
                if (row < N) v = *(const float4*)&X[row * HD + k0 + kq];
                *(float4*)&Xs[r][kq] = v;
            }
        }
        // stage W tile [64 k][128 cols]
        {
            int c4 = (tid & 31) * 4;
            int wr0 = tid >> 5;  // 0..7
#pragma unroll
            for (int p = 0; p < 8; ++p) {
                int wr = wr0 + p * 8;
                *(float4*)&Ws[wr][c4] = *(const float4*)&W[(k0 + wr) * HD + c4];
            }
        }
        __syncthreads();
#pragma unroll 4
        for (int k = 0; k < 64; k += 4) {
            float4 w0 = *(float4*)&Ws[k + 0][tx * 4];
            float4 w1 = *(float4*)&Ws[k + 1][tx * 4];
            float4 w2 = *(float4*)&Ws[k + 2][tx * 4];
            float4 w3 = *(float4*)&Ws[k + 3][tx * 4];
#pragma unroll
            for (int i = 0; i < 8; ++i) {
                float4 a = *(float4*)&Xs[ty * 8 + i][k];
                acc[i].x += a.x * w0.x + a.y * w1.x + a.z * w2.x + a.w * w3.x;
                acc[i].y += a.x * w0.y + a.y * w1.y + a.z * w2.y + a.w * w3.y;
                acc[i].z += a.x * w0.z + a.y * w1.z + a.z * w2.z + a.w * w3.z;
                acc[i].w += a.x * w0.w + a.y * w1.w + a.z * w2.w + a.w * w3.w;
            }
        }
        __syncthreads();
    }

    // store + per-thread stats
    float4 bv = *(const float4*)&bias[tx * 4];
    float s0 = 0.f, s1 = 0.f, s2 = 0.f, s3 = 0.f;
    float q0 = 0.f, q1 = 0.f, q2 = 0.f, q3 = 0.f;
#pragma unroll
    for (int i = 0; i < 8; ++i) {
        int row = rbase + ty * 8 + i;
        if (row < N) {
            float4 o;
            o.x = acc[i].x + bv.x; o.y = acc[i].y + bv.y;
            o.z = acc[i].z + bv.z; o.w = acc[i].w + bv.w;
            *(float4*)&out[row * HD + tx * 4] = o;
            s0 += o.x; s1 += o.y; s2 += o.z; s3 += o.w;
            q0 += o.x * o.x; q1 += o.y * o.y; q2 += o.z * o.z; q3 += o.w * o.w;
        }
    }
    // block reduce over ty (8 partials per column), reuse Xs as scratch
    float* redS = &Xs[0][0];         // [128][8]
    float* redQ = &Xs[0][0] + 1024;  // [128][8]
    int cb = tx * 4;
    redS[(cb + 0) * 8 + ty] = s0; redS[(cb + 1) * 8 + ty] = s1;
    redS[(cb + 2) * 8 + ty] = s2; redS[(cb + 3) * 8 + ty] = s3;
    redQ[(cb + 0) * 8 + ty] = q0; redQ[(cb + 1) * 8 + ty] = q1;
    redQ[(cb + 2) * 8 + ty] = q2; redQ[(cb + 3) * 8 + ty] = q3;
    __syncthreads();
    if (tid < 128) {
        float ss = 0.f, qq = 0.f;
#pragma unroll
        for (int t = 0; t < 8; ++t) { ss += redS[tid * 8 + t]; qq += redQ[tid * 8 + t]; }
        int slot = (blockIdx.x & (NCOPY - 1)) * 256;
        atomicAdd(&stats[slot + tid], ss);
        atomicAdd(&stats[slot + 128 + tid], qq);
    }
}

// ---------------- BN finalize: scale/shift from stats ----------------
__global__ void k_bnfin(const float* __restrict__ stats, const float* __restrict__ gamma,
                        const float* __restrict__ beta, float* __restrict__ bnp, float count) {
    int c = threadIdx.x;  // 128
    float s = 0.f, q = 0.f;
    for (int i = 0; i < NCOPY; ++i) { s += stats[i * 256 + c]; q += stats[i * 256 + 128 + c]; }
    float mean = s / count;
    float var = q / count - mean * mean;
    var = fmaxf(var, 0.f);
    float scale = gamma[c] * rsqrtf(var + 1e-5f);
    bnp[c] = scale;
    bnp[128 + c] = beta[c] - mean * scale;
}

// ---------------- BN apply + LeakyReLU (elementwise, float4) ----------------
__global__ void k_apply(const float* __restrict__ in, const float* __restrict__ bnp,
                        float* __restrict__ outp, int total4) {
    int i = blockIdx.x * blockDim.x + threadIdx.x;
    int stride = gridDim.x * blockDim.x;
    for (int idx = i; idx < total4; idx += stride) {
        int cb = (idx * 4) & (HD - 1);
        float4 v = ((const float4*)in)[idx];
        float4 sc = *(const float4*)&bnp[cb];
        float4 sh = *(const float4*)&bnp[128 + cb];
        float4 o;
        o.x = v.x * sc.x + sh.x; o.y = v.y * sc.y + sh.y;
        o.z = v.z * sc.z + sh.z; o.w = v.w * sc.w + sh.w;
        o.x = (o.x > 0.f) ? o.x : 0.2f * o.x;
        o.y = (o.y > 0.f) ? o.y : 0.2f * o.y;
        o.z = (o.z > 0.f) ? o.z : 0.2f * o.z;
        o.w = (o.w > 0.f) ? o.w : 0.2f * o.w;
        ((float4*)outp)[idx] = o;
    }
}

// ---------------- Pooling: pooled[batch[n]] += h[n] (batch sorted) ----------------
__global__ void k_pool(const float* __restrict__ h, const int* __restrict__ batch,
                       float* __restrict__ pooled, int N) {
    int c = threadIdx.x;  // 128
    int n0 = blockIdx.x * 16;
    if (n0 >= N) return;
    int nend = min(n0 + 16, N);
    float acc = 0.f;
    int cur = batch[n0];
    for (int n = n0; n < nend; ++n) {
        int b = batch[n];
        if (b != cur) { atomicAdd(&pooled[cur * HD + c], acc); acc = 0.f; cur = b; }
        acc += h[n * HD + c];
    }
    atomicAdd(&pooled[cur * HD + c], acc);
}

// ---------------- column stats over pooled [rows][128] ----------------
__global__ void k_colstats(const float* __restrict__ X, float* __restrict__ stats, int rows) {
    int c = threadIdx.x;  // 128
    float s = 0.f, q = 0.f;
    for (int r = blockIdx.x; r < rows; r += gridDim.x) {
        float v = X[r * HD + c];
        s += v; q += v * v;
    }
    int slot = (blockIdx.x & (NCOPY - 1)) * 256;
    atomicAdd(&stats[slot + c], s);
    atomicAdd(&stats[slot + 128 + c], q);
}

// ---------------- final: out[g] = bn2(pooled[g]) @ fcW + fcb ----------------
__global__ void k_final(const float* __restrict__ pooled, const float* __restrict__ bnp,
                        const float* __restrict__ fcW, const float* __restrict__ fcb,
                        float* __restrict__ outp, int G) {
    __shared__ float Wlds[HD * 64];
    __shared__ float prow[HD];
    int tid = threadIdx.x;  // 64
    for (int i = tid; i < HD * 64 / 4; i += 64) ((float4*)Wlds)[i] = ((const float4*)fcW)[i];
    int g = blockIdx.x;
    for (int c = tid; c < HD; c += 64) prow[c] = pooled[g * HD + c] * bnp[c] + bnp[128 + c];
    __syncthreads();
    float acc = fcb[tid];
#pragma unroll 8
    for (int c = 0; c < HD; ++c) acc += prow[c] * Wlds[c * 64 + tid];
    outp[g * 64 + tid] = acc;
}

// ---------------- host orchestration ----------------
extern "C" void kernel_launch(void* const* d_in, const int* in_sizes, int n_in,
                              void* d_out, int out_size, void* d_ws, size_t ws_size,
                              hipStream_t stream) {
    const float* x     = (const float*)d_in[0];
    const int*   ei    = (const int*)d_in[1];
    const int*   batch = (const int*)d_in[2];
    const float* Wl    = (const float*)d_in[3];
    const float* bl    = (const float*)d_in[4];
    const float* Wr    = (const float*)d_in[5];
    const float* bng   = (const float*)d_in[6];
    const float* bnb   = (const float*)d_in[7];
    const float* bn2g  = (const float*)d_in[8];
    const float* bn2b  = (const float*)d_in[9];
    const float* fcW   = (const float*)d_in[10];
    const float* fcb   = (const float*)d_in[11];

    int N = in_sizes[0] / HD;
    int E = in_sizes[1] / 2;
    int G = out_size / 64;
    const int* src = ei;       // edge_index[0]
    const int* dst = ei + E;   // edge_index[1]

    char* p = (char*)d_ws;
    auto alloc = [&](size_t bytes) -> void* {
        void* r = (void*)p;
        p += (bytes + 255) & ~(size_t)255;
        return r;
    };
    int*   degi   = (int*)alloc((size_t)N * 4);
    int*   rowptr = (int*)alloc((size_t)(N + 1) * 4);
    int*   cursor = (int*)alloc((size_t)N * 4);
    int*   bsum   = (int*)alloc(1024);
    int*   boffs  = (int*)alloc(1024);
    int*   csr    = (int*)alloc((size_t)E * 4);
    float* inv    = (float*)alloc((size_t)N * 4);
    float* b0     = (float*)alloc((size_t)N * HD * 4);
    float* b1     = (float*)alloc((size_t)N * HD * 4);
    float* b2     = (float*)alloc((size_t)N * HD * 4);
    float* stats  = (float*)alloc(NCOPY * 256 * 4);
    float* bnp    = (float*)alloc(256 * 4);
    float* pooled = (float*)alloc((size_t)G * HD * 4);

    float* outp = (float*)d_out;

    int nb = (N + 1023) / 1024;

    // CSR build
    hipMemsetAsync(degi, 0, (size_t)N * 4, stream);
    hipMemsetAsync(cursor, 0, (size_t)N * 4, stream);
    k_deg<<<2048, 256, 0, stream>>>(dst, degi, E);
    k_scan1<<<nb, 256, 0, stream>>>(degi, rowptr, bsum, N);
    k_scan2<<<1, 64, 0, stream>>>(bsum, boffs, nb);
    k_scan3<<<1024, 256, 0, stream>>>(rowptr, boffs, N, E);
    k_inv<<<512, 256, 0, stream>>>(degi, inv, N);
    k_fill<<<2048, 256, 0, stream>>>(src, dst, rowptr, cursor, csr, E);

    int ggrid = (N + 63) / 64;
    int total4 = N * HD / 4;

    // layer 0: h_in = x
    k_agg<<<N, HD, 0, stream>>>(x, rowptr, csr, inv, b0, N);
    hipMemsetAsync(stats, 0, NCOPY * 256 * 4, stream);
    k_gemm<<<ggrid, 256, 0, stream>>>(b0, x, Wl, Wr, bl, b1, stats, N);
    k_bnfin<<<1, 128, 0, stream>>>(stats, bng, bnb, bnp, (float)N);
    k_apply<<<2048, 256, 0, stream>>>(b1, bnp, b1, total4);

    // layer 1: h_in = b1
    k_agg<<<N, HD, 0, stream>>>(b1, rowptr, csr, inv, b2, N);
    hipMemsetAsync(stats, 0, NCOPY * 256 * 4, stream);
    k_gemm<<<ggrid, 256, 0, stream>>>(b2, b1, Wl + 16384, Wr + 16384, bl + 128, b0, stats, N);
    k_bnfin<<<1, 128, 0, stream>>>(stats, bng + 128, bnb + 128, bnp, (float)N);
    k_apply<<<2048, 256, 0, stream>>>(b0, bnp, b0, total4);

    // layer 2: h_in = b0
    k_agg<<<N, HD, 0, stream>>>(b0, rowptr, csr, inv, b1, N);
    hipMemsetAsync(stats, 0, NCOPY * 256 * 4, stream);
    k_gemm<<<ggrid, 256, 0, stream>>>(b1, b0, Wl + 32768, Wr + 32768, bl + 256, b2, stats, N);
    k_bnfin<<<1, 128, 0, stream>>>(stats, bng + 256, bnb + 256, bnp, (float)N);
    k_apply<<<2048, 256, 0, stream>>>(b2, bnp, b2, total4);

    // pooling + final BN + FC
    hipMemsetAsync(pooled, 0, (size_t)G * HD * 4, stream);
    k_pool<<<(N + 15) / 16, HD, 0, stream>>>(b2, batch, pooled, N);
    hipMemsetAsync(stats, 0, NCOPY * 256 * 4, stream);
    k_colstats<<<64, HD, 0, stream>>>(pooled, stats, G);
    k_bnfin<<<1, 128, 0, stream>>>(stats, bn2g, bn2b, bnp, (float)G);
    k_final<<<G, 64, 0, stream>>>(pooled, bnp, fcW, fcb, outp, G);
}

// Round 2
// 724.180 us; speedup vs baseline: 1.5781x; 1.5781x over previous
//
#include <hip/hip_runtime.h>

#define HD 128
#define NCOPY 32

typedef __attribute__((ext_vector_type(8))) short short8;
typedef __attribute__((ext_vector_type(4))) float f32x4;

union ABu { unsigned long long u[2]; short8 s8; };

__device__ inline float bf2f(ushort u) {
    union { unsigned int i; float f; } x; x.i = ((unsigned int)u) << 16; return x.f;
}
__device__ inline ushort f2bf(float f) {
    union { float f; unsigned int i; } x; x.f = f;
    unsigned int r = x.i + 0x7FFF + ((x.i >> 16) & 1);
    return (ushort)(r >> 16);
}

// ---------------- CSR build ----------------

__global__ void k_deg(const int* __restrict__ dst, int* __restrict__ degi, int E) {
    int i = blockIdx.x * blockDim.x + threadIdx.x;
    int stride = gridDim.x * blockDim.x;
    for (int e = i; e < E; e += stride) atomicAdd(&degi[dst[e]], 1);
}

__global__ void k_scan1(const int* __restrict__ degi, int* __restrict__ rowptr,
                        int* __restrict__ bsum, int N) {
    __shared__ int lds[256];
    int tid = threadIdx.x;
    int base = blockIdx.x * 1024 + tid * 4;
    int v[4]; int s = 0;
#pragma unroll
    for (int j = 0; j < 4; ++j) { int idx = base + j; v[j] = (idx < N) ? degi[idx] : 0; s += v[j]; }
    lds[tid] = s; __syncthreads();
    for (int off = 1; off < 256; off <<= 1) {
        int t = 0;
        if (tid >= off) t = lds[tid - off];
        __syncthreads();
        if (tid >= off) lds[tid] += t;
        __syncthreads();
    }
    int excl = lds[tid] - s;
#pragma unroll
    for (int j = 0; j < 4; ++j) { int idx = base + j; if (idx < N) rowptr[idx] = excl; excl += v[j]; }
    if (tid == 255) bsum[blockIdx.x] = lds[255];
}

__global__ void k_scan2(const int* __restrict__ bsum, int* __restrict__ boffs, int nb) {
    if (threadIdx.x == 0 && blockIdx.x == 0) {
        int acc = 0;
        for (int i = 0; i < nb; ++i) { boffs[i] = acc; acc += bsum[i]; }
    }
}

__global__ void k_scan3(int* __restrict__ rowptr, const int* __restrict__ boffs, int N, int E) {
    int i = blockIdx.x * blockDim.x + threadIdx.x;
    int stride = gridDim.x * blockDim.x;
    for (int idx = i; idx < N; idx += stride) rowptr[idx] += boffs[idx >> 10];
    if (i == 0) rowptr[N] = E;
}

__global__ void k_inv(const int* __restrict__ degi, float* __restrict__ inv, int N) {
    int i = blockIdx.x * blockDim.x + threadIdx.x;
    int stride = gridDim.x * blockDim.x;
    for (int n = i; n < N; n += stride) inv[n] = (degi[n] > 0) ? (1.0f / (float)degi[n]) : 0.0f;
}

__global__ void k_fill(const int* __restrict__ src, const int* __restrict__ dst,
                       const int* __restrict__ rowptr, int* __restrict__ cursor,
                       int* __restrict__ csr, int E) {
    int i = blockIdx.x * blockDim.x + threadIdx.x;
    int stride = gridDim.x * blockDim.x;
    for (int e = i; e < E; e += stride) {
        int d = dst[e];
        int pos = atomicAdd(&cursor[d], 1);
        csr[rowptr[d] + pos] = src[e];
    }
}

// ---------------- convert fp32 -> bf16 ----------------
__global__ void k_cvt(const float* __restrict__ in, ushort* __restrict__ out, int total4) {
    int i = blockIdx.x * blockDim.x + threadIdx.x;
    int stride = gridDim.x * blockDim.x;
    for (int idx = i; idx < total4; idx += stride) {
        float4 v = ((const float4*)in)[idx];
        ushort4 o;
        o.x = f2bf(v.x); o.y = f2bf(v.y); o.z = f2bf(v.z); o.w = f2bf(v.w);
        ((ushort4*)out)[idx] = o;
    }
}

// WT[l][col][k], k in 0..255 (k<128 -> Wl, else Wr), bf16
__global__ void k_wt(const float* __restrict__ Wl, const float* __restrict__ Wr,
                     ushort* __restrict__ WT, int total) {
    int i = blockIdx.x * blockDim.x + threadIdx.x;
    if (i >= total) return;
    int l = i >> 15;
    int rem = i & 32767;
    int col = rem >> 8;
    int k = rem & 255;
    float v = (k < 128) ? Wl[l * 16384 + k * 128 + col] : Wr[l * 16384 + (k - 128) * 128 + col];
    WT[i] = f2bf(v);
}

// ---------------- Aggregation: agg[n] = mean_{s in N(n)} h[s]  (bf16 in/out) ----------------
// 256 threads/node: 4 waves x 2 edges each in flight; half-wave (32 lanes x ushort4) per row
__global__ __launch_bounds__(256) void k_agg(const ushort* __restrict__ h,
                                             const int* __restrict__ rowptr,
                                             const int* __restrict__ csr,
                                             const float* __restrict__ inv,
                                             ushort* __restrict__ agg, int N) {
    __shared__ float red[4][HD];
    int n = blockIdx.x;
    int tid = threadIdx.x;
    int wid = tid >> 6;
    int lane = tid & 63;
    int half = lane >> 5;
    int ln = lane & 31;
    int beg = rowptr[n], end = rowptr[n + 1];
    float a0 = 0.f, a1 = 0.f, a2 = 0.f, a3 = 0.f;
    for (int e = beg + wid * 2 + half; e < end; e += 8) {
        int s = csr[e];
        ushort4 v = *(const ushort4*)&h[(size_t)s * HD + ln * 4];
        a0 += bf2f(v.x); a1 += bf2f(v.y); a2 += bf2f(v.z); a3 += bf2f(v.w);
    }
    a0 += __shfl_xor(a0, 32); a1 += __shfl_xor(a1, 32);
    a2 += __shfl_xor(a2, 32); a3 += __shfl_xor(a3, 32);
    if (half == 0) {
        red[wid][ln * 4 + 0] = a0; red[wid][ln * 4 + 1] = a1;
        red[wid][ln * 4 + 2] = a2; red[wid][ln * 4 + 3] = a3;
    }
    __syncthreads();
    if (tid < HD) {
        float v = red[0][tid] + red[1][tid] + red[2][tid] + red[3][tid];
        v *= inv[n];
        agg[(size_t)n * HD + tid] = f2bf(v);
    }
}

// ---------------- MFMA dual-GEMM: out = [X1|X2](Nx256) @ WT^T(256x128) + bias ----------------
// 128x128 tile, 4 waves (2x2), 16x16x32 bf16 MFMA, K=256 in 8 chunks of 32.
// LDS row stride 40 ushorts (80B): 16B-aligned staging, 2-way banks on b64 frag reads (free).
__global__ __launch_bounds__(256) void k_gemm(
        const ushort* __restrict__ X1, const ushort* __restrict__ X2,
        const ushort* __restrict__ WT, const float* __restrict__ bias,
        float* __restrict__ out, float* __restrict__ stats, int N) {
    __shared__ ushort As[128 * 40];
    __shared__ ushort Bs[128 * 40];
    int tid = threadIdx.x;
    int lane = tid & 63, wid = tid >> 6;
    int wr = wid >> 1, wc = wid & 1;
    int ln15 = lane & 15, kg = lane >> 4;
    int rbase = blockIdx.x * 128;

    f32x4 acc[4][4];
#pragma unroll
    for (int m = 0; m < 4; ++m)
#pragma unroll
        for (int nn = 0; nn < 4; ++nn) acc[m][nn] = (f32x4){0.f, 0.f, 0.f, 0.f};

    for (int c = 0; c < 8; ++c) {
        const ushort* X = (c < 4) ? X1 : X2;
        int cb = (c & 3) * 32;
        // stage A tile [128 rows][32 k]
#pragma unroll
        for (int p = 0; p < 2; ++p) {
            int g = tid + p * 256;
            int r = g >> 2, q = g & 3;
            int grow = rbase + r;
            uint4 v = {0u, 0u, 0u, 0u};
            if (grow < N) v = *(const uint4*)&X[(size_t)grow * HD + cb + q * 8];
            *(uint4*)&As[r * 40 + q * 8] = v;
        }
        // stage B tile [128 cols][32 k]
#pragma unroll
        for (int p = 0; p < 2; ++p) {
            int g = tid + p * 256;
            int col = g >> 2, q = g & 3;
            *(uint4*)&Bs[col * 40 + q * 8] = *(const uint4*)&WT[col * 256 + c * 32 + q * 8];
        }
        __syncthreads();
        short8 af[4], bfr[4];
#pragma unroll
        for (int m = 0; m < 4; ++m) {
            int row = wr * 64 + m * 16 + ln15;
            const ushort* pa = &As[row * 40 + kg * 4];
            ABu u; u.u[0] = *(const unsigned long long*)pa;
            u.u[1] = *(const unsigned long long*)(pa + 16);
            af[m] = u.s8;
        }
#pragma unroll
        for (int nn = 0; nn < 4; ++nn) {
            int col = wc * 64 + nn * 16 + ln15;
            const ushort* pb = &Bs[col * 40 + kg * 4];
            ABu u; u.u[0] = *(const unsigned long long*)pb;
            u.u[1] = *(const unsigned long long*)(pb + 16);
            bfr[nn] = u.s8;
        }
#pragma unroll
        for (int m = 0; m < 4; ++m)
#pragma unroll
            for (int nn = 0; nn < 4; ++nn)
                acc[m][nn] = __builtin_amdgcn_mfma_f32_16x16x32_bf16(af[m], bfr[nn], acc[m][nn], 0, 0, 0);
        __syncthreads();
    }

    // epilogue: bias + store + column stats
    float s[4] = {0.f, 0.f, 0.f, 0.f};
    float q[4] = {0.f, 0.f, 0.f, 0.f};
    float bv[4];
#pragma unroll
    for (int nn = 0; nn < 4; ++nn) bv[nn] = bias[wc * 64 + nn * 16 + ln15];
#pragma unroll
    for (int m = 0; m < 4; ++m) {
#pragma unroll
        for (int j = 0; j < 4; ++j) {
            int row = rbase + wr * 64 + m * 16 + kg * 4 + j;
            if (row < N) {
#pragma unroll
                for (int nn = 0; nn < 4; ++nn) {
                    float v = acc[m][nn][j] + bv[nn];
                    out[(size_t)row * HD + wc * 64 + nn * 16 + ln15] = v;
                    s[nn] += v; q[nn] += v * v;
                }
            }
        }
    }
#pragma unroll
    for (int nn = 0; nn < 4; ++nn) {
        s[nn] += __shfl_xor(s[nn], 16); s[nn] += __shfl_xor(s[nn], 32);
        q[nn] += __shfl_xor(q[nn], 16); q[nn] += __shfl_xor(q[nn], 32);
    }
    if (lane < 16) {
        int slot = (blockIdx.x & (NCOPY - 1)) * 256;
#pragma unroll
        for (int nn = 0; nn < 4; ++nn) {
            int col = wc * 64 + nn * 16 + lane;
            atomicAdd(&stats[slot + col], s[nn]);
            atomicAdd(&stats[slot + 128 + col], q[nn]);
        }
    }
}

// ---------------- BN finalize ----------------
__global__ void k_bnfin(const float* __restrict__ stats, const float* __restrict__ gamma,
                        const float* __restrict__ beta, float* __restrict__ bnp, float count) {
    int c = threadIdx.x;  // 128
    float s = 0.f, q = 0.f;
    for (int i = 0; i < NCOPY; ++i) { s += stats[i * 256 + c]; q += stats[i * 256 + 128 + c]; }
    float mean = s / count;
    float var = q / count - mean * mean;
    var = fmaxf(var, 0.f);
    float scale = gamma[c] * rsqrtf(var + 1e-5f);
    bnp[c] = scale;
    bnp[128 + c] = beta[c] - mean * scale;
}

// ---------------- BN apply + LeakyReLU: fp32 in -> bf16 out ----------------
__global__ void k_apply(const float* __restrict__ in, const float* __restrict__ bnp,
                        ushort* __restrict__ outp, int total4) {
    int i = blockIdx.x * blockDim.x + threadIdx.x;
    int stride = gridDim.x * blockDim.x;
    for (int idx = i; idx < total4; idx += stride) {
        int cb = (idx * 4) & (HD - 1);
        float4 v = ((const float4*)in)[idx];
        float4 sc = *(const float4*)&bnp[cb];
        float4 sh = *(const float4*)&bnp[128 + cb];
        float4 o;
        o.x = v.x * sc.x + sh.x; o.y = v.y * sc.y + sh.y;
        o.z = v.z * sc.z + sh.z; o.w = v.w * sc.w + sh.w;
        o.x = (o.x > 0.f) ? o.x : 0.2f * o.x;
        o.y = (o.y > 0.f) ? o.y : 0.2f * o.y;
        o.z = (o.z > 0.f) ? o.z : 0.2f * o.z;
        o.w = (o.w > 0.f) ? o.w : 0.2f * o.w;
        ushort4 ob;
        ob.x = f2bf(o.x); ob.y = f2bf(o.y); ob.z = f2bf(o.z); ob.w = f2bf(o.w);
        ((ushort4*)outp)[idx] = ob;
    }
}

// ---------------- Pooling: pooled[batch[n]] += h[n] (batch sorted, h bf16) ----------------
__global__ void k_pool(const ushort* __restrict__ h, const int* __restrict__ batch,
                       float* __restrict__ pooled, int N) {
    int c = threadIdx.x;  // 128
    int n0 = blockIdx.x * 16;
    if (n0 >= N) return;
    int nend = min(n0 + 16, N);
    float acc = 0.f;
    int cur = batch[n0];
    for (int n = n0; n < nend; ++n) {
        int b = batch[n];
        if (b != cur) { atomicAdd(&pooled[cur * HD + c], acc); acc = 0.f; cur = b; }
        acc += bf2f(h[(size_t)n * HD + c]);
    }
    atomicAdd(&pooled[cur * HD + c], acc);
}

// ---------------- column stats over pooled [rows][128] ----------------
__global__ void k_colstats(const float* __restrict__ X, float* __restrict__ stats, int rows) {
    int c = threadIdx.x;  // 128
    float s = 0.f, q = 0.f;
    for (int r = blockIdx.x; r < rows; r += gridDim.x) {
        float v = X[r * HD + c];
        s += v; q += v * v;
    }
    int slot = (blockIdx.x & (NCOPY - 1)) * 256;
    atomicAdd(&stats[slot + c], s);
    atomicAdd(&stats[slot + 128 + c], q);
}

// ---------------- final: out[g] = bn2(pooled[g]) @ fcW + fcb ----------------
__global__ void k_final(const float* __restrict__ pooled, const float* __restrict__ bnp,
                        const float* __restrict__ fcW, const float* __restrict__ fcb,
                        float* __restrict__ outp, int G) {
    __shared__ float Wlds[HD * 64];
    __shared__ float prow[HD];
    int tid = threadIdx.x;  // 64
    for (int i = tid; i < HD * 64 / 4; i += 64) ((float4*)Wlds)[i] = ((const float4*)fcW)[i];
    int g = blockIdx.x;
    for (int c = tid; c < HD; c += 64) prow[c] = pooled[g * HD + c] * bnp[c] + bnp[128 + c];
    __syncthreads();
    float acc = fcb[tid];
#pragma unroll 8
    for (int c = 0; c < HD; ++c) acc += prow[c] * Wlds[c * 64 + tid];
    outp[g * 64 + tid] = acc;
}

// ---------------- host orchestration ----------------
extern "C" void kernel_launch(void* const* d_in, const int* in_sizes, int n_in,
                              void* d_out, int out_size, void* d_ws, size_t ws_size,
                              hipStream_t stream) {
    const float* x     = (const float*)d_in[0];
    const int*   ei    = (const int*)d_in[1];
    const int*   batch = (const int*)d_in[2];
    const float* Wl    = (const float*)d_in[3];
    const float* bl    = (const float*)d_in[4];
    const float* Wr    = (const float*)d_in[5];
    const float* bng   = (const float*)d_in[6];
    const float* bnb   = (const float*)d_in[7];
    const float* bn2g  = (const float*)d_in[8];
    const float* bn2b  = (const float*)d_in[9];
    const float* fcW   = (const float*)d_in[10];
    const float* fcb   = (const float*)d_in[11];

    int N = in_sizes[0] / HD;
    int E = in_sizes[1] / 2;
    int G = out_size / 64;
    const int* src = ei;
    const int* dst = ei + E;

    char* p = (char*)d_ws;
    auto alloc = [&](size_t bytes) -> void* {
        void* r = (void*)p;
        p += (bytes + 255) & ~(size_t)255;
        return r;
    };
    int*    degi   = (int*)alloc((size_t)N * 4);
    int*    rowptr = (int*)alloc((size_t)(N + 1) * 4);
    int*    cursor = (int*)alloc((size_t)N * 4);
    int*    bsum   = (int*)alloc(1024);
    int*    boffs  = (int*)alloc(1024);
    int*    csr    = (int*)alloc((size_t)E * 4);
    float*  inv    = (float*)alloc((size_t)N * 4);
    ushort* WT     = (ushort*)alloc((size_t)3 * 128 * 256 * 2);
    ushort* xb     = (ushort*)alloc((size_t)N * HD * 2);
    ushort* aggb   = (ushort*)alloc((size_t)N * HD * 2);
    ushort* hb1    = (ushort*)alloc((size_t)N * HD * 2);
    ushort* hb2    = (ushort*)alloc((size_t)N * HD * 2);
    float*  gout   = (float*)alloc((size_t)N * HD * 4);
    float*  stats  = (float*)alloc(NCOPY * 256 * 4);
    float*  bnp    = (float*)alloc(256 * 4);
    float*  pooled = (float*)alloc((size_t)G * HD * 4);

    float* outp = (float*)d_out;
    int nb = (N + 1023) / 1024;
    int total4 = N * HD / 4;
    int ggrid = (N + 127) / 128;

    // conversions (independent of CSR)
    k_cvt<<<2048, 256, 0, stream>>>(x, xb, total4);
    k_wt<<<(3 * 128 * 256 + 255) / 256, 256, 0, stream>>>(Wl, Wr, WT, 3 * 128 * 256);

    // CSR build
    hipMemsetAsync(degi, 0, (size_t)N * 4, stream);
    hipMemsetAsync(cursor, 0, (size_t)N * 4, stream);
    k_deg<<<2048, 256, 0, stream>>>(dst, degi, E);
    k_scan1<<<nb, 256, 0, stream>>>(degi, rowptr, bsum, N);
    k_scan2<<<1, 64, 0, stream>>>(bsum, boffs, nb);
    k_scan3<<<1024, 256, 0, stream>>>(rowptr, boffs, N, E);
    k_inv<<<512, 256, 0, stream>>>(degi, inv, N);
    k_fill<<<2048, 256, 0, stream>>>(src, dst, rowptr, cursor, csr, E);

    // layer 0
    k_agg<<<N, 256, 0, stream>>>(xb, rowptr, csr, inv, aggb, N);
    hipMemsetAsync(stats, 0, NCOPY * 256 * 4, stream);
    k_gemm<<<ggrid, 256, 0, stream>>>(aggb, xb, WT, bl, gout, stats, N);
    k_bnfin<<<1, 128, 0, stream>>>(stats, bng, bnb, bnp, (float)N);
    k_apply<<<2048, 256, 0, stream>>>(gout, bnp, hb1, total4);

    // layer 1
    k_agg<<<N, 256, 0, stream>>>(hb1, rowptr, csr, inv, aggb, N);
    hipMemsetAsync(stats, 0, NCOPY * 256 * 4, stream);
    k_gemm<<<ggrid, 256, 0, stream>>>(aggb, hb1, WT + 32768, bl + 128, gout, stats, N);
    k_bnfin<<<1, 128, 0, stream>>>(stats, bng + 128, bnb + 128, bnp, (float)N);
    k_apply<<<2048, 256, 0, stream>>>(gout, bnp, hb2, total4);

    // layer 2
    k_agg<<<N, 256, 0, stream>>>(hb2, rowptr, csr, inv, aggb, N);
    hipMemsetAsync(stats, 0, NCOPY * 256 * 4, stream);
    k_gemm<<<ggrid, 256, 0, stream>>>(aggb, hb2, WT + 65536, bl + 256, gout, stats, N);
    k_bnfin<<<1, 128, 0, stream>>>(stats, bng + 256, bnb + 256, bnp, (float)N);
    k_apply<<<2048, 256, 0, stream>>>(gout, bnp, hb1, total4);

    // pooling + final BN + FC
    hipMemsetAsync(pooled, 0, (size_t)G * HD * 4, stream);
    k_pool<<<(N + 15) / 16, HD, 0, stream>>>(hb1, batch, pooled, N);
    hipMemsetAsync(stats, 0, NCOPY * 256 * 4, stream);
    k_colstats<<<64, HD, 0, stream>>>(pooled, stats, G);
    k_bnfin<<<1, 128, 0, stream>>>(stats, bn2g, bn2b, bnp, (float)G);
    k_final<<<G, 64, 0, stream>>>(pooled, bnp, fcW, fcb, outp, G);
}

// Round 3
// 534.955 us; speedup vs baseline: 2.1363x; 1.3537x over previous
//
#include <hip/hip_runtime.h>

#define HD 128
#define NCOPY 32

typedef __attribute__((ext_vector_type(8))) short short8;
typedef __attribute__((ext_vector_type(4))) float f32x4;

union ABu { unsigned long long u[2]; short8 s8; };

__device__ inline float bf2f(ushort u) {
    union { unsigned int i; float f; } x; x.i = ((unsigned int)u) << 16; return x.f;
}
__device__ inline float bflo(unsigned int u) {
    union { unsigned int i; float f; } x; x.i = u << 16; return x.f;
}
__device__ inline float bfhi(unsigned int u) {
    union { unsigned int i; float f; } x; x.i = u & 0xffff0000u; return x.f;
}
__device__ inline ushort f2bf(float f) {
    union { float f; unsigned int i; } x; x.f = f;
    unsigned int r = x.i + 0x7FFF + ((x.i >> 16) & 1);
    return (ushort)(r >> 16);
}

// ---------------- CSR build ----------------

__global__ void k_deg(const int* __restrict__ dst, int* __restrict__ degi, int E) {
    int i = blockIdx.x * blockDim.x + threadIdx.x;
    int stride = gridDim.x * blockDim.x;
    for (int e = i; e < E; e += stride) atomicAdd(&degi[dst[e]], 1);
}

__global__ void k_scan1(const int* __restrict__ degi, int* __restrict__ rowptr,
                        int* __restrict__ bsum, int N) {
    __shared__ int lds[256];
    int tid = threadIdx.x;
    int base = blockIdx.x * 1024 + tid * 4;
    int v[4]; int s = 0;
#pragma unroll
    for (int j = 0; j < 4; ++j) { int idx = base + j; v[j] = (idx < N) ? degi[idx] : 0; s += v[j]; }
    lds[tid] = s; __syncthreads();
    for (int off = 1; off < 256; off <<= 1) {
        int t = 0;
        if (tid >= off) t = lds[tid - off];
        __syncthreads();
        if (tid >= off) lds[tid] += t;
        __syncthreads();
    }
    int excl = lds[tid] - s;
#pragma unroll
    for (int j = 0; j < 4; ++j) { int idx = base + j; if (idx < N) rowptr[idx] = excl; excl += v[j]; }
    if (tid == 255) bsum[blockIdx.x] = lds[255];
}

__global__ void k_scan2(const int* __restrict__ bsum, int* __restrict__ boffs, int nb) {
    if (threadIdx.x == 0 && blockIdx.x == 0) {
        int acc = 0;
        for (int i = 0; i < nb; ++i) { boffs[i] = acc; acc += bsum[i]; }
    }
}

__global__ void k_scan3(int* __restrict__ rowptr, const int* __restrict__ boffs, int N, int E) {
    int i = blockIdx.x * blockDim.x + threadIdx.x;
    int stride = gridDim.x * blockDim.x;
    for (int idx = i; idx < N; idx += stride) rowptr[idx] += boffs[idx >> 10];
    if (i == 0) rowptr[N] = E;
}

__global__ void k_inv(const int* __restrict__ degi, float* __restrict__ inv, int N) {
    int i = blockIdx.x * blockDim.x + threadIdx.x;
    int stride = gridDim.x * blockDim.x;
    for (int n = i; n < N; n += stride) inv[n] = (degi[n] > 0) ? (1.0f / (float)degi[n]) : 0.0f;
}

__global__ void k_fill(const int* __restrict__ src, const int* __restrict__ dst,
                       const int* __restrict__ rowptr, int* __restrict__ cursor,
                       int* __restrict__ csr, int E) {
    int i = blockIdx.x * blockDim.x + threadIdx.x;
    int stride = gridDim.x * blockDim.x;
    for (int e = i; e < E; e += stride) {
        int d = dst[e];
        int pos = atomicAdd(&cursor[d], 1);
        csr[rowptr[d] + pos] = src[e];
    }
}

// ---------------- convert fp32 -> bf16 ----------------
__global__ void k_cvt(const float* __restrict__ in, ushort* __restrict__ out, int total4) {
    int i = blockIdx.x * blockDim.x + threadIdx.x;
    int stride = gridDim.x * blockDim.x;
    for (int idx = i; idx < total4; idx += stride) {
        float4 v = ((const float4*)in)[idx];
        ushort4 o;
        o.x = f2bf(v.x); o.y = f2bf(v.y); o.z = f2bf(v.z); o.w = f2bf(v.w);
        ((ushort4*)out)[idx] = o;
    }
}

// WT[l][col][k], k in 0..255 (k<128 -> Wl, else Wr), bf16
__global__ void k_wt(const float* __restrict__ Wl, const float* __restrict__ Wr,
                     ushort* __restrict__ WT, int total) {
    int i = blockIdx.x * blockDim.x + threadIdx.x;
    if (i >= total) return;
    int l = i >> 15;
    int rem = i & 32767;
    int col = rem >> 8;
    int k = rem & 255;
    float v = (k < 128) ? Wl[l * 16384 + k * 128 + col] : Wr[l * 16384 + (k - 128) * 128 + col];
    WT[i] = f2bf(v);
}

// ---------------- Aggregation v3: one wave per node, 8 rows in flight ----------------
// wave: 4 edge-groups x 16 lanes; lane loads ushort8 (16B); 2-deep unroll per group.
__global__ __launch_bounds__(256) void k_agg(const ushort* __restrict__ h,
                                             const int* __restrict__ rowptr,
                                             const int* __restrict__ csr,
                                             const float* __restrict__ inv,
                                             ushort* __restrict__ agg, int N) {
    int node = blockIdx.x * 4 + (threadIdx.x >> 6);
    if (node >= N) return;
    int lane = threadIdx.x & 63;
    int g = lane >> 4, ln = lane & 15;
    int beg = rowptr[node], end = rowptr[node + 1];
    float a[8], b[8];
#pragma unroll
    for (int j = 0; j < 8; ++j) { a[j] = 0.f; b[j] = 0.f; }
    for (int e = beg + g; e < end; e += 8) {
        int s0 = csr[e];
        uint4 v0 = *(const uint4*)&h[(size_t)s0 * HD + ln * 8];
        int e1 = e + 4;
        if (e1 < end) {
            int s1 = csr[e1];
            uint4 v1 = *(const uint4*)&h[(size_t)s1 * HD + ln * 8];
            b[0] += bflo(v1.x); b[1] += bfhi(v1.x);
            b[2] += bflo(v1.y); b[3] += bfhi(v1.y);
            b[4] += bflo(v1.z); b[5] += bfhi(v1.z);
            b[6] += bflo(v1.w); b[7] += bfhi(v1.w);
        }
        a[0] += bflo(v0.x); a[1] += bfhi(v0.x);
        a[2] += bflo(v0.y); a[3] += bfhi(v0.y);
        a[4] += bflo(v0.z); a[5] += bfhi(v0.z);
        a[6] += bflo(v0.w); a[7] += bfhi(v0.w);
    }
#pragma unroll
    for (int j = 0; j < 8; ++j) {
        a[j] += b[j];
        a[j] += __shfl_xor(a[j], 16);
        a[j] += __shfl_xor(a[j], 32);
    }
    if (lane < 16) {
        float iv = inv[node];
        ushort o[8];
#pragma unroll
        for (int j = 0; j < 8; ++j) o[j] = f2bf(a[j] * iv);
        *(uint4*)&agg[(size_t)node * HD + ln * 8] = *(uint4*)o;
    }
}

// ---------------- MFMA dual-GEMM: out = [X1|X2](Nx256) @ WT^T(256x128) + bias ----------------
// 128x128 tile, 4 waves (2x2), 16x16x32 bf16 MFMA, K=256 in 8 chunks of 32.
// Output stored as bf16 (pre-BN); column stats accumulated in fp32.
__global__ __launch_bounds__(256) void k_gemm(
        const ushort* __restrict__ X1, const ushort* __restrict__ X2,
        const ushort* __restrict__ WT, const float* __restrict__ bias,
        ushort* __restrict__ out, float* __restrict__ stats, int N) {
    __shared__ ushort As[128 * 40];
    __shared__ ushort Bs[128 * 40];
    int tid = threadIdx.x;
    int lane = tid & 63, wid = tid >> 6;
    int wr = wid >> 1, wc = wid & 1;
    int ln15 = lane & 15, kg = lane >> 4;
    int rbase = blockIdx.x * 128;

    f32x4 acc[4][4];
#pragma unroll
    for (int m = 0; m < 4; ++m)
#pragma unroll
        for (int nn = 0; nn < 4; ++nn) acc[m][nn] = (f32x4){0.f, 0.f, 0.f, 0.f};

    for (int c = 0; c < 8; ++c) {
        const ushort* X = (c < 4) ? X1 : X2;
        int cb = (c & 3) * 32;
#pragma unroll
        for (int p = 0; p < 2; ++p) {
            int g = tid + p * 256;
            int r = g >> 2, q = g & 3;
            int grow = rbase + r;
            uint4 v = {0u, 0u, 0u, 0u};
            if (grow < N) v = *(const uint4*)&X[(size_t)grow * HD + cb + q * 8];
            *(uint4*)&As[r * 40 + q * 8] = v;
        }
#pragma unroll
        for (int p = 0; p < 2; ++p) {
            int g = tid + p * 256;
            int col = g >> 2, q = g & 3;
            *(uint4*)&Bs[col * 40 + q * 8] = *(const uint4*)&WT[col * 256 + c * 32 + q * 8];
        }
        __syncthreads();
        short8 af[4], bfr[4];
#pragma unroll
        for (int m = 0; m < 4; ++m) {
            int row = wr * 64 + m * 16 + ln15;
            const ushort* pa = &As[row * 40 + kg * 4];
            ABu u; u.u[0] = *(const unsigned long long*)pa;
            u.u[1] = *(const unsigned long long*)(pa + 16);
            af[m] = u.s8;
        }
#pragma unroll
        for (int nn = 0; nn < 4; ++nn) {
            int col = wc * 64 + nn * 16 + ln15;
            const ushort* pb = &Bs[col * 40 + kg * 4];
            ABu u; u.u[0] = *(const unsigned long long*)pb;
            u.u[1] = *(const unsigned long long*)(pb + 16);
            bfr[nn] = u.s8;
        }
#pragma unroll
        for (int m = 0; m < 4; ++m)
#pragma unroll
            for (int nn = 0; nn < 4; ++nn)
                acc[m][nn] = __builtin_amdgcn_mfma_f32_16x16x32_bf16(af[m], bfr[nn], acc[m][nn], 0, 0, 0);
        __syncthreads();
    }

    // epilogue: bias + bf16 store + column stats
    float s[4] = {0.f, 0.f, 0.f, 0.f};
    float q[4] = {0.f, 0.f, 0.f, 0.f};
    float bv[4];
#pragma unroll
    for (int nn = 0; nn < 4; ++nn) bv[nn] = bias[wc * 64 + nn * 16 + ln15];
#pragma unroll
    for (int m = 0; m < 4; ++m) {
#pragma unroll
        for (int j = 0; j < 4; ++j) {
            int row = rbase + wr * 64 + m * 16 + kg * 4 + j;
            if (row < N) {
#pragma unroll
                for (int nn = 0; nn < 4; ++nn) {
                    float v = acc[m][nn][j] + bv[nn];
                    out[(size_t)row * HD + wc * 64 + nn * 16 + ln15] = f2bf(v);
                    s[nn] += v; q[nn] += v * v;
                }
            }
        }
    }
#pragma unroll
    for (int nn = 0; nn < 4; ++nn) {
        s[nn] += __shfl_xor(s[nn], 16); s[nn] += __shfl_xor(s[nn], 32);
        q[nn] += __shfl_xor(q[nn], 16); q[nn] += __shfl_xor(q[nn], 32);
    }
    if (lane < 16) {
        int slot = (blockIdx.x & (NCOPY - 1)) * 256;
#pragma unroll
        for (int nn = 0; nn < 4; ++nn) {
            int col = wc * 64 + nn * 16 + lane;
            atomicAdd(&stats[slot + col], s[nn]);
            atomicAdd(&stats[slot + 128 + col], q[nn]);
        }
    }
}

// ---------------- BN finalize ----------------
__global__ void k_bnfin(const float* __restrict__ stats, const float* __restrict__ gamma,
                        const float* __restrict__ beta, float* __restrict__ bnp, float count) {
    int c = threadIdx.x;  // 128
    float s = 0.f, q = 0.f;
    for (int i = 0; i < NCOPY; ++i) { s += stats[i * 256 + c]; q += stats[i * 256 + 128 + c]; }
    float mean = s / count;
    float var = q / count - mean * mean;
    var = fmaxf(var, 0.f);
    float scale = gamma[c] * rsqrtf(var + 1e-5f);
    bnp[c] = scale;
    bnp[128 + c] = beta[c] - mean * scale;
}

// ---------------- BN apply + LeakyReLU: bf16 in -> bf16 out ----------------
__global__ void k_apply(const ushort* __restrict__ in, const float* __restrict__ bnp,
                        ushort* __restrict__ outp, int total8) {
    int i = blockIdx.x * blockDim.x + threadIdx.x;
    int stride = gridDim.x * blockDim.x;
    for (int idx = i; idx < total8; idx += stride) {
        int cb = (idx * 8) & (HD - 1);
        uint4 v = ((const uint4*)in)[idx];
        float f[8];
        f[0] = bflo(v.x); f[1] = bfhi(v.x);
        f[2] = bflo(v.y); f[3] = bfhi(v.y);
        f[4] = bflo(v.z); f[5] = bfhi(v.z);
        f[6] = bflo(v.w); f[7] = bfhi(v.w);
        ushort o[8];
#pragma unroll
        for (int j = 0; j < 8; ++j) {
            float y = f[j] * bnp[cb + j] + bnp[128 + cb + j];
            y = (y > 0.f) ? y : 0.2f * y;
            o[j] = f2bf(y);
        }
        ((uint4*)outp)[idx] = *(uint4*)o;
    }
}

// ---------------- Pooling: pooled[batch[n]] += h[n] (batch sorted, h bf16) ----------------
__global__ void k_pool(const ushort* __restrict__ h, const int* __restrict__ batch,
                       float* __restrict__ pooled, int N) {
    int c = threadIdx.x;  // 128
    int n0 = blockIdx.x * 16;
    if (n0 >= N) return;
    int nend = min(n0 + 16, N);
    float acc = 0.f;
    int cur = batch[n0];
    for (int n = n0; n < nend; ++n) {
        int b = batch[n];
        if (b != cur) { atomicAdd(&pooled[cur * HD + c], acc); acc = 0.f; cur = b; }
        acc += bf2f(h[(size_t)n * HD + c]);
    }
    atomicAdd(&pooled[cur * HD + c], acc);
}

// ---------------- column stats over pooled [rows][128] ----------------
__global__ void k_colstats(const float* __restrict__ X, float* __restrict__ stats, int rows) {
    int c = threadIdx.x;  // 128
    float s = 0.f, q = 0.f;
    for (int r = blockIdx.x; r < rows; r += gridDim.x) {
        float v = X[r * HD + c];
        s += v; q += v * v;
    }
    int slot = (blockIdx.x & (NCOPY - 1)) * 256;
    atomicAdd(&stats[slot + c], s);
    atomicAdd(&stats[slot + 128 + c], q);
}

// ---------------- final: out[g] = bn2(pooled[g]) @ fcW + fcb ----------------
__global__ void k_final(const float* __restrict__ pooled, const float* __restrict__ bnp,
                        const float* __restrict__ fcW, const float* __restrict__ fcb,
                        float* __restrict__ outp, int G) {
    __shared__ float Wlds[HD * 64];
    __shared__ float prow[HD];
    int tid = threadIdx.x;  // 64
    for (int i = tid; i < HD * 64 / 4; i += 64) ((float4*)Wlds)[i] = ((const float4*)fcW)[i];
    int g = blockIdx.x;
    for (int c = tid; c < HD; c += 64) prow[c] = pooled[g * HD + c] * bnp[c] + bnp[128 + c];
    __syncthreads();
    float acc = fcb[tid];
#pragma unroll 8
    for (int c = 0; c < HD; ++c) acc += prow[c] * Wlds[c * 64 + tid];
    outp[g * 64 + tid] = acc;
}

// ---------------- host orchestration ----------------
extern "C" void kernel_launch(void* const* d_in, const int* in_sizes, int n_in,
                              void* d_out, int out_size, void* d_ws, size_t ws_size,
                              hipStream_t stream) {
    const float* x     = (const float*)d_in[0];
    const int*   ei    = (const int*)d_in[1];
    const int*   batch = (const int*)d_in[2];
    const float* Wl    = (const float*)d_in[3];
    const float* bl    = (const float*)d_in[4];
    const float* Wr    = (const float*)d_in[5];
    const float* bng   = (const float*)d_in[6];
    const float* bnb   = (const float*)d_in[7];
    const float* bn2g  = (const float*)d_in[8];
    const float* bn2b  = (const float*)d_in[9];
    const float* fcW   = (const float*)d_in[10];
    const float* fcb   = (const float*)d_in[11];

    int N = in_sizes[0] / HD;
    int E = in_sizes[1] / 2;
    int G = out_size / 64;
    const int* src = ei;
    const int* dst = ei + E;

    char* p = (char*)d_ws;
    auto alloc = [&](size_t bytes) -> void* {
        void* r = (void*)p;
        p += (bytes + 255) & ~(size_t)255;
        return r;
    };
    int*    degi   = (int*)alloc((size_t)N * 4);
    int*    rowptr = (int*)alloc((size_t)(N + 1) * 4);
    int*    cursor = (int*)alloc((size_t)N * 4);
    int*    bsum   = (int*)alloc(1024);
    int*    boffs  = (int*)alloc(1024);
    int*    csr    = (int*)alloc((size_t)E * 4);
    float*  inv    = (float*)alloc((size_t)N * 4);
    ushort* WT     = (ushort*)alloc((size_t)3 * 128 * 256 * 2);
    ushort* xb     = (ushort*)alloc((size_t)N * HD * 2);
    ushort* aggb   = (ushort*)alloc((size_t)N * HD * 2);
    ushort* hb1    = (ushort*)alloc((size_t)N * HD * 2);
    ushort* hb2    = (ushort*)alloc((size_t)N * HD * 2);
    ushort* goutb  = (ushort*)alloc((size_t)N * HD * 2);
    float*  stats  = (float*)alloc(NCOPY * 256 * 4);
    float*  bnp    = (float*)alloc(256 * 4);
    float*  pooled = (float*)alloc((size_t)G * HD * 4);

    float* outp = (float*)d_out;
    int nb = (N + 1023) / 1024;
    int total4 = N * HD / 4;
    int total8 = N * HD / 8;
    int ggrid = (N + 127) / 128;
    int agrid = (N + 3) / 4;

    k_cvt<<<2048, 256, 0, stream>>>(x, xb, total4);
    k_wt<<<(3 * 128 * 256 + 255) / 256, 256, 0, stream>>>(Wl, Wr, WT, 3 * 128 * 256);

    hipMemsetAsync(degi, 0, (size_t)N * 4, stream);
    hipMemsetAsync(cursor, 0, (size_t)N * 4, stream);
    k_deg<<<2048, 256, 0, stream>>>(dst, degi, E);
    k_scan1<<<nb, 256, 0, stream>>>(degi, rowptr, bsum, N);
    k_scan2<<<1, 64, 0, stream>>>(bsum, boffs, nb);
    k_scan3<<<1024, 256, 0, stream>>>(rowptr, boffs, N, E);
    k_inv<<<512, 256, 0, stream>>>(degi, inv, N);
    k_fill<<<2048, 256, 0, stream>>>(src, dst, rowptr, cursor, csr, E);

    // layer 0
    k_agg<<<agrid, 256, 0, stream>>>(xb, rowptr, csr, inv, aggb, N);
    hipMemsetAsync(stats, 0, NCOPY * 256 * 4, stream);
    k_gemm<<<ggrid, 256, 0, stream>>>(aggb, xb, WT, bl, goutb, stats, N);
    k_bnfin<<<1, 128, 0, stream>>>(stats, bng, bnb, bnp, (float)N);
    k_apply<<<2048, 256, 0, stream>>>(goutb, bnp, hb1, total8);

    // layer 1
    k_agg<<<agrid, 256, 0, stream>>>(hb1, rowptr, csr, inv, aggb, N);
    hipMemsetAsync(stats, 0, NCOPY * 256 * 4, stream);
    k_gemm<<<ggrid, 256, 0, stream>>>(aggb, hb1, WT + 32768, bl + 128, goutb, stats, N);
    k_bnfin<<<1, 128, 0, stream>>>(stats, bng + 128, bnb + 128, bnp, (float)N);
    k_apply<<<2048, 256, 0, stream>>>(goutb, bnp, hb2, total8);

    // layer 2
    k_agg<<<agrid, 256, 0, stream>>>(hb2, rowptr, csr, inv, aggb, N);
    hipMemsetAsync(stats, 0, NCOPY * 256 * 4, stream);
    k_gemm<<<ggrid, 256, 0, stream>>>(aggb, hb2, WT + 65536, bl + 256, goutb, stats, N);
    k_bnfin<<<1, 128, 0, stream>>>(stats, bng + 256, bnb + 256, bnp, (float)N);
    k_apply<<<2048, 256, 0, stream>>>(goutb, bnp, hb1, total8);

    // pooling + final BN + FC
    hipMemsetAsync(pooled, 0, (size_t)G * HD * 4, stream);
    k_pool<<<(N + 15) / 16, HD, 0, stream>>>(hb1, batch, pooled, N);
    hipMemsetAsync(stats, 0, NCOPY * 256 * 4, stream);
    k_colstats<<<64, HD, 0, stream>>>(pooled, stats, G);
    k_bnfin<<<1, 128, 0, stream>>>(stats, bn2g, bn2b, bnp, (float)G);
    k_final<<<G, 64, 0, stream>>>(pooled, bnp, fcW, fcb, outp, G);
}

// Round 5
// 428.974 us; speedup vs baseline: 2.6641x; 1.2471x over previous
//
#include <hip/hip_runtime.h>

#define HD 128
#define NCOPY 32
#define BSH 8
#define BSZ 256
#define EPB 4096

typedef __attribute__((ext_vector_type(8))) short short8;
typedef __attribute__((ext_vector_type(4))) float f32x4;

union ABu { unsigned long long u[2]; short8 s8; };

__device__ inline float bf2f(ushort u) {
    union { unsigned int i; float f; } x; x.i = ((unsigned int)u) << 16; return x.f;
}
__device__ inline float bflo(unsigned int u) {
    union { unsigned int i; float f; } x; x.i = u << 16; return x.f;
}
__device__ inline float bfhi(unsigned int u) {
    union { unsigned int i; float f; } x; x.i = u & 0xffff0000u; return x.f;
}
__device__ inline ushort f2bf(float f) {
    union { float f; unsigned int i; } x; x.f = f;
    unsigned int r = x.i + 0x7FFF + ((x.i >> 16) & 1);
    return (ushort)(r >> 16);
}

// ---------------- Bucketed CSR build ----------------
// bucket = dst >> BSH (256 nodes / bucket). Packed edge word: src | (dst&255)<<17.

__global__ __launch_bounds__(256) void kp_count(const int* __restrict__ dst,
                                                int* __restrict__ bucketCount, int E, int NB) {
    __shared__ int hist[512];
    for (int i = threadIdx.x; i < NB; i += 256) hist[i] = 0;
    __syncthreads();
    int e0 = blockIdx.x * EPB;
#pragma unroll
    for (int j = 0; j < 16; ++j) {
        int e = e0 + j * 256 + threadIdx.x;
        if (e < E) atomicAdd(&hist[dst[e] >> BSH], 1);
    }
    __syncthreads();
    for (int i = threadIdx.x; i < NB; i += 256)
        if (hist[i]) atomicAdd(&bucketCount[i], hist[i]);
}

// single block, 512 threads: exclusive scan of bucketCount (NB <= 512)
__global__ void kp_scan(const int* __restrict__ bucketCount, int* __restrict__ bucketBase,
                        int* __restrict__ gCursor, int NB, int E) {
    __shared__ int lds[512];
    int tid = threadIdx.x;
    int v = (tid < NB) ? bucketCount[tid] : 0;
    lds[tid] = v;
    __syncthreads();
    for (int off = 1; off < 512; off <<= 1) {
        int t = 0;
        if (tid >= off) t = lds[tid - off];
        __syncthreads();
        if (tid >= off) lds[tid] += t;
        __syncthreads();
    }
    int excl = lds[tid] - v;
    if (tid < NB) { bucketBase[tid] = excl; gCursor[tid] = excl; }
    if (tid == 0) bucketBase[NB] = E;
}

__global__ __launch_bounds__(256) void kp_part(const int* __restrict__ src,
                                               const int* __restrict__ dst,
                                               int* __restrict__ gCursor,
                                               unsigned int* __restrict__ packed, int E, int NB) {
    __shared__ int hist[512], lbase[512], lcur[512];
    for (int i = threadIdx.x; i < NB; i += 256) hist[i] = 0;
    __syncthreads();
    int e0 = blockIdx.x * EPB;
    int b[16]; unsigned int w[16];
#pragma unroll
    for (int j = 0; j < 16; ++j) {
        int e = e0 + j * 256 + threadIdx.x;
        b[j] = -1;
        if (e < E) {
            int d = dst[e];
            int s = src[e];
            b[j] = d >> BSH;
            w[j] = (unsigned int)s | (((unsigned int)d & (BSZ - 1)) << 17);
            atomicAdd(&hist[b[j]], 1);
        }
    }
    __syncthreads();
    for (int i = threadIdx.x; i < NB; i += 256) {
        int c = hist[i];
        lbase[i] = c ? atomicAdd(&gCursor[i], c) : 0;
        lcur[i] = 0;
    }
    __syncthreads();
#pragma unroll
    for (int j = 0; j < 16; ++j) {
        if (b[j] >= 0) {
            int r = atomicAdd(&lcur[b[j]], 1);
            packed[lbase[b[j]] + r] = w[j];
        }
    }
}

// one block per bucket: per-node degree via LDS counters, coalesced write
__global__ __launch_bounds__(256) void kp_deg(const unsigned int* __restrict__ packed,
                                              const int* __restrict__ bucketBase,
                                              int* __restrict__ deg, int N) {
    __shared__ int dcnt[BSZ];
    int bkt = blockIdx.x;
    int n0 = bkt << BSH;
    for (int i = threadIdx.x; i < BSZ; i += 256) dcnt[i] = 0;
    __syncthreads();
    int beg = bucketBase[bkt], end = bucketBase[bkt + 1];
    for (int e = beg + threadIdx.x; e < end; e += 256)
        atomicAdd(&dcnt[packed[e] >> 17], 1);
    __syncthreads();
    for (int i = threadIdx.x; i < BSZ; i += 256) {
        int n = n0 + i;
        if (n < N) deg[n] = dcnt[i];
    }
}

// one block per bucket: place srcs; cursor + rowptr window in LDS, csr writes L2-local
__global__ __launch_bounds__(256) void kp_fill(const unsigned int* __restrict__ packed,
                                               const int* __restrict__ bucketBase,
                                               const int* __restrict__ rowptr,
                                               int* __restrict__ csr, int N) {
    __shared__ int rp[BSZ];
    __shared__ int cur[BSZ];
    int bkt = blockIdx.x;
    int n0 = bkt << BSH;
    for (int i = threadIdx.x; i < BSZ; i += 256) {
        int n = n0 + i;
        rp[i] = (n < N) ? rowptr[n] : 0;
        cur[i] = 0;
    }
    __syncthreads();
    int beg = bucketBase[bkt], end = bucketBase[bkt + 1];
    for (int e = beg + threadIdx.x; e < end; e += 256) {
        unsigned int wv = packed[e];
        int ld = wv >> 17;
        int s = (int)(wv & 0x1FFFF);
        int p = atomicAdd(&cur[ld], 1);
        csr[rp[ld] + p] = s;
    }
}

// ---------------- rowptr scan (over deg) ----------------

__global__ void k_scan1(const int* __restrict__ degi, int* __restrict__ rowptr,
                        int* __restrict__ bsum, int N) {
    __shared__ int lds[256];
    int tid = threadIdx.x;
    int base = blockIdx.x * 1024 + tid * 4;
    int v[4]; int s = 0;
#pragma unroll
    for (int j = 0; j < 4; ++j) { int idx = base + j; v[j] = (idx < N) ? degi[idx] : 0; s += v[j]; }
    lds[tid] = s; __syncthreads();
    for (int off = 1; off < 256; off <<= 1) {
        int t = 0;
        if (tid >= off) t = lds[tid - off];
        __syncthreads();
        if (tid >= off) lds[tid] += t;
        __syncthreads();
    }
    int excl = lds[tid] - s;
#pragma unroll
    for (int j = 0; j < 4; ++j) { int idx = base + j; if (idx < N) rowptr[idx] = excl; excl += v[j]; }
    if (tid == 255) bsum[blockIdx.x] = lds[255];
}

__global__ void k_scan2(const int* __restrict__ bsum, int* __restrict__ boffs, int nb) {
    if (threadIdx.x == 0 && blockIdx.x == 0) {
        int acc = 0;
        for (int i = 0; i < nb; ++i) { boffs[i] = acc; acc += bsum[i]; }
    }
}

__global__ void k_scan3(int* __restrict__ rowptr, const int* __restrict__ boffs, int N, int E) {
    int i = blockIdx.x * blockDim.x + threadIdx.x;
    int stride = gridDim.x * blockDim.x;
    for (int idx = i; idx < N; idx += stride) rowptr[idx] += boffs[idx >> 10];
    if (i == 0) rowptr[N] = E;
}

__global__ void k_inv(const int* __restrict__ degi, float* __restrict__ inv, int N) {
    int i = blockIdx.x * blockDim.x + threadIdx.x;
    int stride = gridDim.x * blockDim.x;
    for (int n = i; n < N; n += stride) inv[n] = (degi[n] > 0) ? (1.0f / (float)degi[n]) : 0.0f;
}

// ---------------- convert fp32 -> bf16 ----------------
__global__ void k_cvt(const float* __restrict__ in, ushort* __restrict__ out, int total4) {
    int i = blockIdx.x * blockDim.x + threadIdx.x;
    int stride = gridDim.x * blockDim.x;
    for (int idx = i; idx < total4; idx += stride) {
        float4 v = ((const float4*)in)[idx];
        ushort4 o;
        o.x = f2bf(v.x); o.y = f2bf(v.y); o.z = f2bf(v.z); o.w = f2bf(v.w);
        ((ushort4*)out)[idx] = o;
    }
}

// WT[l][col][k], k in 0..255 (k<128 -> Wl, else Wr), bf16
__global__ void k_wt(const float* __restrict__ Wl, const float* __restrict__ Wr,
                     ushort* __restrict__ WT, int total) {
    int i = blockIdx.x * blockDim.x + threadIdx.x;
    if (i >= total) return;
    int l = i >> 15;
    int rem = i & 32767;
    int col = rem >> 8;
    int k = rem & 255;
    float v = (k < 128) ? Wl[l * 16384 + k * 128 + col] : Wr[l * 16384 + (k - 128) * 128 + col];
    WT[i] = f2bf(v);
}

// ---------------- Aggregation: one wave per node, 8 rows in flight ----------------
__global__ __launch_bounds__(256) void k_agg(const ushort* __restrict__ h,
                                             const int* __restrict__ rowptr,
                                             const int* __restrict__ csr,
                                             const float* __restrict__ inv,
                                             ushort* __restrict__ agg, int N) {
    int node = blockIdx.x * 4 + (threadIdx.x >> 6);
    if (node >= N) return;
    int lane = threadIdx.x & 63;
    int g = lane >> 4, ln = lane & 15;
    int beg = rowptr[node], end = rowptr[node + 1];
    float a[8], b[8];
#pragma unroll
    for (int j = 0; j < 8; ++j) { a[j] = 0.f; b[j] = 0.f; }
    for (int e = beg + g; e < end; e += 8) {
        int s0 = csr[e];
        uint4 v0 = *(const uint4*)&h[(size_t)s0 * HD + ln * 8];
        int e1 = e + 4;
        if (e1 < end) {
            int s1 = csr[e1];
            uint4 v1 = *(const uint4*)&h[(size_t)s1 * HD + ln * 8];
            b[0] += bflo(v1.x); b[1] += bfhi(v1.x);
            b[2] += bflo(v1.y); b[3] += bfhi(v1.y);
            b[4] += bflo(v1.z); b[5] += bfhi(v1.z);
            b[6] += bflo(v1.w); b[7] += bfhi(v1.w);
        }
        a[0] += bflo(v0.x); a[1] += bfhi(v0.x);
        a[2] += bflo(v0.y); a[3] += bfhi(v0.y);
        a[4] += bflo(v0.z); a[5] += bfhi(v0.z);
        a[6] += bflo(v0.w); a[7] += bfhi(v0.w);
    }
#pragma unroll
    for (int j = 0; j < 8; ++j) {
        a[j] += b[j];
        a[j] += __shfl_xor(a[j], 16);
        a[j] += __shfl_xor(a[j], 32);
    }
    if (lane < 16) {
        float iv = inv[node];
        ushort o[8];
#pragma unroll
        for (int j = 0; j < 8; ++j) o[j] = f2bf(a[j] * iv);
        *(uint4*)&agg[(size_t)node * HD + ln * 8] = *(uint4*)o;
    }
}

// ---------------- MFMA dual-GEMM: out = [X1|X2](Nx256) @ WT^T(256x128) + bias ----------------
__global__ __launch_bounds__(256) void k_gemm(
        const ushort* __restrict__ X1, const ushort* __restrict__ X2,
        const ushort* __restrict__ WT, const float* __restrict__ bias,
        ushort* __restrict__ out, float* __restrict__ stats, int N) {
    __shared__ ushort As[128 * 40];
    __shared__ ushort Bs[128 * 40];
    int tid = threadIdx.x;
    int lane = tid & 63, wid = tid >> 6;
    int wr = wid >> 1, wc = wid & 1;
    int ln15 = lane & 15, kg = lane >> 4;
    int rbase = blockIdx.x * 128;

    f32x4 acc[4][4];
#pragma unroll
    for (int m = 0; m < 4; ++m)
#pragma unroll
        for (int nn = 0; nn < 4; ++nn) acc[m][nn] = (f32x4){0.f, 0.f, 0.f, 0.f};

    for (int c = 0; c < 8; ++c) {
        const ushort* X = (c < 4) ? X1 : X2;
        int cb = (c & 3) * 32;
#pragma unroll
        for (int p = 0; p < 2; ++p) {
            int g = tid + p * 256;
            int r = g >> 2, q = g & 3;
            int grow = rbase + r;
            uint4 v = {0u, 0u, 0u, 0u};
            if (grow < N) v = *(const uint4*)&X[(size_t)grow * HD + cb + q * 8];
            *(uint4*)&As[r * 40 + q * 8] = v;
        }
#pragma unroll
        for (int p = 0; p < 2; ++p) {
            int g = tid + p * 256;
            int col = g >> 2, q = g & 3;
            *(uint4*)&Bs[col * 40 + q * 8] = *(const uint4*)&WT[col * 256 + c * 32 + q * 8];
        }
        __syncthreads();
        short8 af[4], bfr[4];
#pragma unroll
        for (int m = 0; m < 4; ++m) {
            int row = wr * 64 + m * 16 + ln15;
            const ushort* pa = &As[row * 40 + kg * 4];
            ABu u; u.u[0] = *(const unsigned long long*)pa;
            u.u[1] = *(const unsigned long long*)(pa + 16);
            af[m] = u.s8;
        }
#pragma unroll
        for (int nn = 0; nn < 4; ++nn) {
            int col = wc * 64 + nn * 16 + ln15;
            const ushort* pb = &Bs[col * 40 + kg * 4];
            ABu u; u.u[0] = *(const unsigned long long*)pb;
            u.u[1] = *(const unsigned long long*)(pb + 16);
            bfr[nn] = u.s8;
        }
#pragma unroll
        for (int m = 0; m < 4; ++m)
#pragma unroll
            for (int nn = 0; nn < 4; ++nn)
                acc[m][nn] = __builtin_amdgcn_mfma_f32_16x16x32_bf16(af[m], bfr[nn], acc[m][nn], 0, 0, 0);
        __syncthreads();
    }

    float s[4] = {0.f, 0.f, 0.f, 0.f};
    float q[4] = {0.f, 0.f, 0.f, 0.f};
    float bv[4];
#pragma unroll
    for (int nn = 0; nn < 4; ++nn) bv[nn] = bias[wc * 64 + nn * 16 + ln15];
#pragma unroll
    for (int m = 0; m < 4; ++m) {
#pragma unroll
        for (int j = 0; j < 4; ++j) {
            int row = rbase + wr * 64 + m * 16 + kg * 4 + j;
            if (row < N) {
#pragma unroll
                for (int nn = 0; nn < 4; ++nn) {
                    float v = acc[m][nn][j] + bv[nn];
                    out[(size_t)row * HD + wc * 64 + nn * 16 + ln15] = f2bf(v);
                    s[nn] += v; q[nn] += v * v;
                }
            }
        }
    }
#pragma unroll
    for (int nn = 0; nn < 4; ++nn) {
        s[nn] += __shfl_xor(s[nn], 16); s[nn] += __shfl_xor(s[nn], 32);
        q[nn] += __shfl_xor(q[nn], 16); q[nn] += __shfl_xor(q[nn], 32);
    }
    if (lane < 16) {
        int slot = (blockIdx.x & (NCOPY - 1)) * 256;
#pragma unroll
        for (int nn = 0; nn < 4; ++nn) {
            int col = wc * 64 + nn * 16 + lane;
            atomicAdd(&stats[slot + col], s[nn]);
            atomicAdd(&stats[slot + 128 + col], q[nn]);
        }
    }
}

// ---------------- BN finalize ----------------
__global__ void k_bnfin(const float* __restrict__ stats, const float* __restrict__ gamma,
                        const float* __restrict__ beta, float* __restrict__ bnp, float count) {
    int c = threadIdx.x;  // 128
    float s = 0.f, q = 0.f;
    for (int i = 0; i < NCOPY; ++i) { s += stats[i * 256 + c]; q += stats[i * 256 + 128 + c]; }
    float mean = s / count;
    float var = q / count - mean * mean;
    var = fmaxf(var, 0.f);
    float scale = gamma[c] * rsqrtf(var + 1e-5f);
    bnp[c] = scale;
    bnp[128 + c] = beta[c] - mean * scale;
}

// ---------------- BN apply + LeakyReLU, IN-PLACE on bf16 buffer ----------------
__global__ void k_apply(ushort* buf, const float* __restrict__ bnp, int total8) {
    int i = blockIdx.x * blockDim.x + threadIdx.x;
    int stride = gridDim.x * blockDim.x;
    for (int idx = i; idx < total8; idx += stride) {
        int cb = (idx * 8) & (HD - 1);
        uint4 v = ((const uint4*)buf)[idx];
        float f[8];
        f[0] = bflo(v.x); f[1] = bfhi(v.x);
        f[2] = bflo(v.y); f[3] = bfhi(v.y);
        f[4] = bflo(v.z); f[5] = bfhi(v.z);
        f[6] = bflo(v.w); f[7] = bfhi(v.w);
        ushort o[8];
#pragma unroll
        for (int j = 0; j < 8; ++j) {
            float y = f[j] * bnp[cb + j] + bnp[128 + cb + j];
            y = (y > 0.f) ? y : 0.2f * y;
            o[j] = f2bf(y);
        }
        ((uint4*)buf)[idx] = *(uint4*)o;
    }
}

// ---------------- Pooling: pooled[batch[n]] += h[n] (batch sorted, h bf16) ----------------
__global__ void k_pool(const ushort* __restrict__ h, const int* __restrict__ batch,
                       float* __restrict__ pooled, int N) {
    int c = threadIdx.x;  // 128
    int n0 = blockIdx.x * 16;
    if (n0 >= N) return;
    int nend = min(n0 + 16, N);
    float acc = 0.f;
    int cur = batch[n0];
    for (int n = n0; n < nend; ++n) {
        int b = batch[n];
        if (b != cur) { atomicAdd(&pooled[cur * HD + c], acc); acc = 0.f; cur = b; }
        acc += bf2f(h[(size_t)n * HD + c]);
    }
    atomicAdd(&pooled[cur * HD + c], acc);
}

// ---------------- column stats over pooled [rows][128] ----------------
__global__ void k_colstats(const float* __restrict__ X, float* __restrict__ stats, int rows) {
    int c = threadIdx.x;  // 128
    float s = 0.f, q = 0.f;
    for (int r = blockIdx.x; r < rows; r += gridDim.x) {
        float v = X[r * HD + c];
        s += v; q += v * v;
    }
    int slot = (blockIdx.x & (NCOPY - 1)) * 256;
    atomicAdd(&stats[slot + c], s);
    atomicAdd(&stats[slot + 128 + c], q);
}

// ---------------- final: out[g] = bn2(pooled[g]) @ fcW + fcb ----------------
__global__ void k_final(const float* __restrict__ pooled, const float* __restrict__ bnp,
                        const float* __restrict__ fcW, const float* __restrict__ fcb,
                        float* __restrict__ outp, int G) {
    __shared__ float Wlds[HD * 64];
    __shared__ float prow[HD];
    int tid = threadIdx.x;  // 64
    for (int i = tid; i < HD * 64 / 4; i += 64) ((float4*)Wlds)[i] = ((const float4*)fcW)[i];
    int g = blockIdx.x;
    for (int c = tid; c < HD; c += 64) prow[c] = pooled[g * HD + c] * bnp[c] + bnp[128 + c];
    __syncthreads();
    float acc = fcb[tid];
#pragma unroll 8
    for (int c = 0; c < HD; ++c) acc += prow[c] * Wlds[c * 64 + tid];
    outp[g * 64 + tid] = acc;
}

// ---------------- host orchestration ----------------
extern "C" void kernel_launch(void* const* d_in, const int* in_sizes, int n_in,
                              void* d_out, int out_size, void* d_ws, size_t ws_size,
                              hipStream_t stream) {
    const float* x     = (const float*)d_in[0];
    const int*   ei    = (const int*)d_in[1];
    const int*   batch = (const int*)d_in[2];
    const float* Wl    = (const float*)d_in[3];
    const float* bl    = (const float*)d_in[4];
    const float* Wr    = (const float*)d_in[5];
    const float* bng   = (const float*)d_in[6];
    const float* bnb   = (const float*)d_in[7];
    const float* bn2g  = (const float*)d_in[8];
    const float* bn2b  = (const float*)d_in[9];
    const float* fcW   = (const float*)d_in[10];
    const float* fcb   = (const float*)d_in[11];

    int N = in_sizes[0] / HD;
    int E = in_sizes[1] / 2;
    int G = out_size / 64;
    const int* src = ei;
    const int* dst = ei + E;

    char* p = (char*)d_ws;
    auto alloc = [&](size_t bytes) -> void* {
        void* r = (void*)p;
        p += (bytes + 255) & ~(size_t)255;
        return r;
    };
    int NB = (N + BSZ - 1) >> BSH;   // buckets (<=512 for N<=131072)
    int nPB = (E + EPB - 1) / EPB;

    int*    degi    = (int*)alloc((size_t)N * 4);
    int*    rowptr  = (int*)alloc((size_t)(N + 1) * 4);
    int*    bCount  = (int*)alloc((size_t)NB * 4);
    int*    bBase   = (int*)alloc((size_t)(NB + 1) * 4);
    int*    gCursor = (int*)alloc((size_t)NB * 4);
    int*    bsum    = (int*)alloc(1024);
    int*    boffs   = (int*)alloc(1024);
    int*    csr     = (int*)alloc((size_t)E * 4);
    float*  inv     = (float*)alloc((size_t)N * 4);
    ushort* WT      = (ushort*)alloc((size_t)3 * 128 * 256 * 2);
    ushort* xb      = (ushort*)alloc((size_t)N * HD * 2);
    ushort* aggb    = (ushort*)alloc((size_t)N * HD * 2);
    ushort* hb1     = (ushort*)alloc((size_t)N * HD * 2);
    ushort* hb2     = (ushort*)alloc((size_t)N * HD * 2);
    float*  stats   = (float*)alloc(NCOPY * 256 * 4);
    float*  bnp     = (float*)alloc(256 * 4);
    float*  pooled  = (float*)alloc((size_t)G * HD * 4);

    // packed edge list overlays aggb: dead before first k_agg writes aggb (stream-ordered)
    unsigned int* packed = (unsigned int*)aggb;

    float* outp = (float*)d_out;
    int nb = (N + 1023) / 1024;
    int total4 = N * HD / 4;
    int total8 = N * HD / 8;
    int ggrid = (N + 127) / 128;
    int agrid = (N + 3) / 4;

    k_cvt<<<2048, 256, 0, stream>>>(x, xb, total4);
    k_wt<<<(3 * 128 * 256 + 255) / 256, 256, 0, stream>>>(Wl, Wr, WT, 3 * 128 * 256);

    // bucketed CSR build
    hipMemsetAsync(bCount, 0, (size_t)NB * 4, stream);
    kp_count<<<nPB, 256, 0, stream>>>(dst, bCount, E, NB);
    kp_scan<<<1, 512, 0, stream>>>(bCount, bBase, gCursor, NB, E);
    kp_part<<<nPB, 256, 0, stream>>>(src, dst, gCursor, packed, E, NB);
    kp_deg<<<NB, 256, 0, stream>>>(packed, bBase, degi, N);
    k_scan1<<<nb, 256, 0, stream>>>(degi, rowptr, bsum, N);
    k_scan2<<<1, 64, 0, stream>>>(bsum, boffs, nb);
    k_scan3<<<1024, 256, 0, stream>>>(rowptr, boffs, N, E);
    k_inv<<<512, 256, 0, stream>>>(degi, inv, N);
    kp_fill<<<NB, 256, 0, stream>>>(packed, bBase, rowptr, csr, N);

    // layer 0: h=xb -> hb1
    k_agg<<<agrid, 256, 0, stream>>>(xb, rowptr, csr, inv, aggb, N);
    hipMemsetAsync(stats, 0, NCOPY * 256 * 4, stream);
    k_gemm<<<ggrid, 256, 0, stream>>>(aggb, xb, WT, bl, hb1, stats, N);
    k_bnfin<<<1, 128, 0, stream>>>(stats, bng, bnb, bnp, (float)N);
    k_apply<<<2048, 256, 0, stream>>>(hb1, bnp, total8);

    // layer 1: h=hb1 -> hb2
    k_agg<<<agrid, 256, 0, stream>>>(hb1, rowptr, csr, inv, aggb, N);
    hipMemsetAsync(stats, 0, NCOPY * 256 * 4, stream);
    k_gemm<<<ggrid, 256, 0, stream>>>(aggb, hb1, WT + 32768, bl + 128, hb2, stats, N);
    k_bnfin<<<1, 128, 0, stream>>>(stats, bng + 128, bnb + 128, bnp, (float)N);
    k_apply<<<2048, 256, 0, stream>>>(hb2, bnp, total8);

    // layer 2: h=hb2 -> hb1 (hb1 dead after layer-1 gemm)
    k_agg<<<agrid, 256, 0, stream>>>(hb2, rowptr, csr, inv, aggb, N);
    hipMemsetAsync(stats, 0, NCOPY * 256 * 4, stream);
    k_gemm<<<ggrid, 256, 0, stream>>>(aggb, hb2, WT + 65536, bl + 256, hb1, stats, N);
    k_bnfin<<<1, 128, 0, stream>>>(stats, bng + 256, bnb + 256, bnp, (float)N);
    k_apply<<<2048, 256, 0, stream>>>(hb1, bnp, total8);

    // pooling + final BN + FC
    hipMemsetAsync(pooled, 0, (size_t)G * HD * 4, stream);
    k_pool<<<(N + 15) / 16, HD, 0, stream>>>(hb1, batch, pooled, N);
    hipMemsetAsync(stats, 0, NCOPY * 256 * 4, stream);
    k_colstats<<<64, HD, 0, stream>>>(pooled, stats, G);
    k_bnfin<<<1, 128, 0, stream>>>(stats, bn2g, bn2b, bnp, (float)G);
    k_final<<<G, 64, 0, stream>>>(pooled, bnp, fcW, fcb, outp, G);
}

// Round 6
// 420.753 us; speedup vs baseline: 2.7162x; 1.0195x over previous
//
#include <hip/hip_runtime.h>

#define HD 128
#define NCOPY 32
#define BSH 8
#define BSZ 256
#define EPB 4096

typedef __attribute__((ext_vector_type(8))) short short8;
typedef __attribute__((ext_vector_type(4))) float f32x4;

union ABu { unsigned long long u[2]; short8 s8; };

__device__ inline float bf2f(ushort u) {
    union { unsigned int i; float f; } x; x.i = ((unsigned int)u) << 16; return x.f;
}
__device__ inline float bflo(unsigned int u) {
    union { unsigned int i; float f; } x; x.i = u << 16; return x.f;
}
__device__ inline float bfhi(unsigned int u) {
    union { unsigned int i; float f; } x; x.i = u & 0xffff0000u; return x.f;
}
__device__ inline ushort f2bf(float f) {
    union { float f; unsigned int i; } x; x.f = f;
    unsigned int r = x.i + 0x7FFF + ((x.i >> 16) & 1);
    return (ushort)(r >> 16);
}

// ---------------- Bucketed CSR build ----------------
// bucket = dst >> BSH (256 nodes / bucket). Packed edge word: src | (dst&255)<<17.

__global__ __launch_bounds__(256) void kp_count(const int* __restrict__ dst,
                                                int* __restrict__ bucketCount, int E, int NB) {
    __shared__ int hist[512];
    for (int i = threadIdx.x; i < NB; i += 256) hist[i] = 0;
    __syncthreads();
    int e0 = blockIdx.x * EPB;
#pragma unroll
    for (int j = 0; j < 16; ++j) {
        int e = e0 + j * 256 + threadIdx.x;
        if (e < E) atomicAdd(&hist[dst[e] >> BSH], 1);
    }
    __syncthreads();
    for (int i = threadIdx.x; i < NB; i += 256)
        if (hist[i]) atomicAdd(&bucketCount[i], hist[i]);
}

// single block, 512 threads: exclusive scan of bucketCount (NB <= 512)
__global__ void kp_scan(const int* __restrict__ bucketCount, int* __restrict__ bucketBase,
                        int* __restrict__ gCursor, int NB, int E) {
    __shared__ int lds[512];
    int tid = threadIdx.x;
    int v = (tid < NB) ? bucketCount[tid] : 0;
    lds[tid] = v;
    __syncthreads();
    for (int off = 1; off < 512; off <<= 1) {
        int t = 0;
        if (tid >= off) t = lds[tid - off];
        __syncthreads();
        if (tid >= off) lds[tid] += t;
        __syncthreads();
    }
    int excl = lds[tid] - v;
    if (tid < NB) { bucketBase[tid] = excl; gCursor[tid] = excl; }
    if (tid == 0) bucketBase[NB] = E;
}

__global__ __launch_bounds__(256) void kp_part(const int* __restrict__ src,
                                               const int* __restrict__ dst,
                                               int* __restrict__ gCursor,
                                               unsigned int* __restrict__ packed, int E, int NB) {
    __shared__ int hist[512], lbase[512], lcur[512];
    for (int i = threadIdx.x; i < NB; i += 256) hist[i] = 0;
    __syncthreads();
    int e0 = blockIdx.x * EPB;
    int b[16]; unsigned int w[16];
#pragma unroll
    for (int j = 0; j < 16; ++j) {
        int e = e0 + j * 256 + threadIdx.x;
        b[j] = -1;
        if (e < E) {
            int d = dst[e];
            int s = src[e];
            b[j] = d >> BSH;
            w[j] = (unsigned int)s | (((unsigned int)d & (BSZ - 1)) << 17);
            atomicAdd(&hist[b[j]], 1);
        }
    }
    __syncthreads();
    for (int i = threadIdx.x; i < NB; i += 256) {
        int c = hist[i];
        lbase[i] = c ? atomicAdd(&gCursor[i], c) : 0;
        lcur[i] = 0;
    }
    __syncthreads();
#pragma unroll
    for (int j = 0; j < 16; ++j) {
        if (b[j] >= 0) {
            int r = atomicAdd(&lcur[b[j]], 1);
            packed[lbase[b[j]] + r] = w[j];
        }
    }
}

// one block per bucket: per-node degree + intra-bucket scan -> rowptr, inv directly
__global__ __launch_bounds__(256) void kp_degscan(const unsigned int* __restrict__ packed,
                                                  const int* __restrict__ bucketBase,
                                                  int* __restrict__ rowptr,
                                                  float* __restrict__ inv, int N, int E) {
    __shared__ int dcnt[BSZ];
    __shared__ int scn[BSZ];
    int bkt = blockIdx.x;
    int tid = threadIdx.x;
    int n0 = bkt << BSH;
    dcnt[tid] = 0;
    __syncthreads();
    int beg = bucketBase[bkt], end = bucketBase[bkt + 1];
    for (int e = beg + tid; e < end; e += 256)
        atomicAdd(&dcnt[packed[e] >> 17], 1);
    __syncthreads();
    int v = dcnt[tid];
    scn[tid] = v;
    __syncthreads();
    for (int off = 1; off < 256; off <<= 1) {
        int t = 0;
        if (tid >= off) t = scn[tid - off];
        __syncthreads();
        if (tid >= off) scn[tid] += t;
        __syncthreads();
    }
    int n = n0 + tid;
    if (n < N) {
        rowptr[n] = beg + scn[tid] - v;
        inv[n] = (v > 0) ? (1.0f / (float)v) : 0.0f;
    }
    if (bkt == 0 && tid == 0) rowptr[N] = E;
}

// one block per bucket: place srcs; cursor + rowptr window in LDS, csr writes L2-local
__global__ __launch_bounds__(256) void kp_fill(const unsigned int* __restrict__ packed,
                                               const int* __restrict__ bucketBase,
                                               const int* __restrict__ rowptr,
                                               int* __restrict__ csr, int N) {
    __shared__ int rp[BSZ];
    __shared__ int cur[BSZ];
    int bkt = blockIdx.x;
    int n0 = bkt << BSH;
    for (int i = threadIdx.x; i < BSZ; i += 256) {
        int n = n0 + i;
        rp[i] = (n < N) ? rowptr[n] : 0;
        cur[i] = 0;
    }
    __syncthreads();
    int beg = bucketBase[bkt], end = bucketBase[bkt + 1];
    for (int e = beg + threadIdx.x; e < end; e += 256) {
        unsigned int wv = packed[e];
        int ld = wv >> 17;
        int s = (int)(wv & 0x1FFFF);
        int p = atomicAdd(&cur[ld], 1);
        csr[rp[ld] + p] = s;
    }
}

// ---------------- convert fp32 -> bf16 ----------------
__global__ void k_cvt(const float* __restrict__ in, ushort* __restrict__ out, int total4) {
    int i = blockIdx.x * blockDim.x + threadIdx.x;
    int stride = gridDim.x * blockDim.x;
    for (int idx = i; idx < total4; idx += stride) {
        float4 v = ((const float4*)in)[idx];
        ushort4 o;
        o.x = f2bf(v.x); o.y = f2bf(v.y); o.z = f2bf(v.z); o.w = f2bf(v.w);
        ((ushort4*)out)[idx] = o;
    }
}

// WT[l][col][k], k in 0..255 (k<128 -> Wl, else Wr), bf16
__global__ void k_wt(const float* __restrict__ Wl, const float* __restrict__ Wr,
                     ushort* __restrict__ WT, int total) {
    int i = blockIdx.x * blockDim.x + threadIdx.x;
    if (i >= total) return;
    int l = i >> 15;
    int rem = i & 32767;
    int col = rem >> 8;
    int k = rem & 255;
    float v = (k < 128) ? Wl[l * 16384 + k * 128 + col] : Wr[l * 16384 + (k - 128) * 128 + col];
    WT[i] = f2bf(v);
}

// ---------------- Aggregation: one wave per node, 16 rows in flight ----------------
// 4 edge-groups x 16 lanes; lane loads ushort8 (16B); 4-deep unroll per group.
__global__ __launch_bounds__(256) void k_agg(const ushort* __restrict__ h,
                                             const int* __restrict__ rowptr,
                                             const int* __restrict__ csr,
                                             const float* __restrict__ inv,
                                             ushort* __restrict__ agg, int N) {
    int node = blockIdx.x * 4 + (threadIdx.x >> 6);
    if (node >= N) return;
    int lane = threadIdx.x & 63;
    int g = lane >> 4, ln = lane & 15;
    int beg = rowptr[node], end = rowptr[node + 1];
    float a[8], b[8], c[8], d[8];
#pragma unroll
    for (int j = 0; j < 8; ++j) { a[j] = 0.f; b[j] = 0.f; c[j] = 0.f; d[j] = 0.f; }
    for (int e = beg + g; e < end; e += 16) {
        int s0 = csr[e];
        uint4 v0 = *(const uint4*)&h[(size_t)s0 * HD + ln * 8];
        int e1 = e + 4, e2 = e + 8, e3 = e + 12;
        if (e1 < end) {
            int s1 = csr[e1];
            uint4 v1 = *(const uint4*)&h[(size_t)s1 * HD + ln * 8];
            b[0] += bflo(v1.x); b[1] += bfhi(v1.x);
            b[2] += bflo(v1.y); b[3] += bfhi(v1.y);
            b[4] += bflo(v1.z); b[5] += bfhi(v1.z);
            b[6] += bflo(v1.w); b[7] += bfhi(v1.w);
        }
        if (e2 < end) {
            int s2 = csr[e2];
            uint4 v2 = *(const uint4*)&h[(size_t)s2 * HD + ln * 8];
            c[0] += bflo(v2.x); c[1] += bfhi(v2.x);
            c[2] += bflo(v2.y); c[3] += bfhi(v2.y);
            c[4] += bflo(v2.z); c[5] += bfhi(v2.z);
            c[6] += bflo(v2.w); c[7] += bfhi(v2.w);
        }
        if (e3 < end) {
            int s3 = csr[e3];
            uint4 v3 = *(const uint4*)&h[(size_t)s3 * HD + ln * 8];
            d[0] += bflo(v3.x); d[1] += bfhi(v3.x);
            d[2] += bflo(v3.y); d[3] += bfhi(v3.y);
            d[4] += bflo(v3.z); d[5] += bfhi(v3.z);
            d[6] += bflo(v3.w); d[7] += bfhi(v3.w);
        }
        a[0] += bflo(v0.x); a[1] += bfhi(v0.x);
        a[2] += bflo(v0.y); a[3] += bfhi(v0.y);
        a[4] += bflo(v0.z); a[5] += bfhi(v0.z);
        a[6] += bflo(v0.w); a[7] += bfhi(v0.w);
    }
#pragma unroll
    for (int j = 0; j < 8; ++j) {
        a[j] += b[j] + (c[j] + d[j]);
        a[j] += __shfl_xor(a[j], 16);
        a[j] += __shfl_xor(a[j], 32);
    }
    if (lane < 16) {
        float iv = inv[node];
        ushort o[8];
#pragma unroll
        for (int j = 0; j < 8; ++j) o[j] = f2bf(a[j] * iv);
        *(uint4*)&agg[(size_t)node * HD + ln * 8] = *(uint4*)o;
    }
}

// ---------------- MFMA dual-GEMM: out = [X1|X2](Nx256) @ WT^T(256x128) + bias ----------------
__global__ __launch_bounds__(256) void k_gemm(
        const ushort* __restrict__ X1, const ushort* __restrict__ X2,
        const ushort* __restrict__ WT, const float* __restrict__ bias,
        ushort* __restrict__ out, float* __restrict__ stats, int N) {
    __shared__ ushort As[128 * 40];
    __shared__ ushort Bs[128 * 40];
    int tid = threadIdx.x;
    int lane = tid & 63, wid = tid >> 6;
    int wr = wid >> 1, wc = wid & 1;
    int ln15 = lane & 15, kg = lane >> 4;
    int rbase = blockIdx.x * 128;

    f32x4 acc[4][4];
#pragma unroll
    for (int m = 0; m < 4; ++m)
#pragma unroll
        for (int nn = 0; nn < 4; ++nn) acc[m][nn] = (f32x4){0.f, 0.f, 0.f, 0.f};

    for (int c = 0; c < 8; ++c) {
        const ushort* X = (c < 4) ? X1 : X2;
        int cb = (c & 3) * 32;
#pragma unroll
        for (int p = 0; p < 2; ++p) {
            int g = tid + p * 256;
            int r = g >> 2, q = g & 3;
            int grow = rbase + r;
            uint4 v = {0u, 0u, 0u, 0u};
            if (grow < N) v = *(const uint4*)&X[(size_t)grow * HD + cb + q * 8];
            *(uint4*)&As[r * 40 + q * 8] = v;
        }
#pragma unroll
        for (int p = 0; p < 2; ++p) {
            int g = tid + p * 256;
            int col = g >> 2, q = g & 3;
            *(uint4*)&Bs[col * 40 + q * 8] = *(const uint4*)&WT[col * 256 + c * 32 + q * 8];
        }
        __syncthreads();
        short8 af[4], bfr[4];
#pragma unroll
        for (int m = 0; m < 4; ++m) {
            int row = wr * 64 + m * 16 + ln15;
            const ushort* pa = &As[row * 40 + kg * 4];
            ABu u; u.u[0] = *(const unsigned long long*)pa;
            u.u[1] = *(const unsigned long long*)(pa + 16);
            af[m] = u.s8;
        }
#pragma unroll
        for (int nn = 0; nn < 4; ++nn) {
            int col = wc * 64 + nn * 16 + ln15;
            const ushort* pb = &Bs[col * 40 + kg * 4];
            ABu u; u.u[0] = *(const unsigned long long*)pb;
            u.u[1] = *(const unsigned long long*)(pb + 16);
            bfr[nn] = u.s8;
        }
#pragma unroll
        for (int m = 0; m < 4; ++m)
#pragma unroll
            for (int nn = 0; nn < 4; ++nn)
                acc[m][nn] = __builtin_amdgcn_mfma_f32_16x16x32_bf16(af[m], bfr[nn], acc[m][nn], 0, 0, 0);
        __syncthreads();
    }

    float s[4] = {0.f, 0.f, 0.f, 0.f};
    float q[4] = {0.f, 0.f, 0.f, 0.f};
    float bv[4];
#pragma unroll
    for (int nn = 0; nn < 4; ++nn) bv[nn] = bias[wc * 64 + nn * 16 + ln15];
#pragma unroll
    for (int m = 0; m < 4; ++m) {
#pragma unroll
        for (int j = 0; j < 4; ++j) {
            int row = rbase + wr * 64 + m * 16 + kg * 4 + j;
            if (row < N) {
#pragma unroll
                for (int nn = 0; nn < 4; ++nn) {
                    float v = acc[m][nn][j] + bv[nn];
                    out[(size_t)row * HD + wc * 64 + nn * 16 + ln15] = f2bf(v);
                    s[nn] += v; q[nn] += v * v;
                }
            }
        }
    }
#pragma unroll
    for (int nn = 0; nn < 4; ++nn) {
        s[nn] += __shfl_xor(s[nn], 16); s[nn] += __shfl_xor(s[nn], 32);
        q[nn] += __shfl_xor(q[nn], 16); q[nn] += __shfl_xor(q[nn], 32);
    }
    if (lane < 16) {
        int slot = (blockIdx.x & (NCOPY - 1)) * 256;
#pragma unroll
        for (int nn = 0; nn < 4; ++nn) {
            int col = wc * 64 + nn * 16 + lane;
            atomicAdd(&stats[slot + col], s[nn]);
            atomicAdd(&stats[slot + 128 + col], q[nn]);
        }
    }
}

// ---------------- BN finalize ----------------
__global__ void k_bnfin(const float* __restrict__ stats, const float* __restrict__ gamma,
                        const float* __restrict__ beta, float* __restrict__ bnp, float count) {
    int c = threadIdx.x;  // 128
    float s = 0.f, q = 0.f;
    for (int i = 0; i < NCOPY; ++i) { s += stats[i * 256 + c]; q += stats[i * 256 + 128 + c]; }
    float mean = s / count;
    float var = q / count - mean * mean;
    var = fmaxf(var, 0.f);
    float scale = gamma[c] * rsqrtf(var + 1e-5f);
    bnp[c] = scale;
    bnp[128 + c] = beta[c] - mean * scale;
}

// ---------------- BN apply + LeakyReLU, IN-PLACE on bf16 buffer ----------------
__global__ void k_apply(ushort* buf, const float* __restrict__ bnp, int total8) {
    int i = blockIdx.x * blockDim.x + threadIdx.x;
    int stride = gridDim.x * blockDim.x;
    for (int idx = i; idx < total8; idx += stride) {
        int cb = (idx * 8) & (HD - 1);
        uint4 v = ((const uint4*)buf)[idx];
        float f[8];
        f[0] = bflo(v.x); f[1] = bfhi(v.x);
        f[2] = bflo(v.y); f[3] = bfhi(v.y);
        f[4] = bflo(v.z); f[5] = bfhi(v.z);
        f[6] = bflo(v.w); f[7] = bfhi(v.w);
        ushort o[8];
#pragma unroll
        for (int j = 0; j < 8; ++j) {
            float y = f[j] * bnp[cb + j] + bnp[128 + cb + j];
            y = (y > 0.f) ? y : 0.2f * y;
            o[j] = f2bf(y);
        }
        ((uint4*)buf)[idx] = *(uint4*)o;
    }
}

// ---------------- Pooling with fused BN+LeakyReLU (batch sorted, h = pre-BN bf16) --------
__global__ void k_poolapply(const ushort* __restrict__ h, const float* __restrict__ bnp,
                            const int* __restrict__ batch, float* __restrict__ pooled, int N) {
    int c = threadIdx.x;  // 128
    float sc = bnp[c], sh = bnp[128 + c];
    int n0 = blockIdx.x * 16;
    if (n0 >= N) return;
    int nend = min(n0 + 16, N);
    float acc = 0.f;
    int cur = batch[n0];
    for (int n = n0; n < nend; ++n) {
        int b = batch[n];
        if (b != cur) { atomicAdd(&pooled[cur * HD + c], acc); acc = 0.f; cur = b; }
        float y = bf2f(h[(size_t)n * HD + c]) * sc + sh;
        y = (y > 0.f) ? y : 0.2f * y;
        acc += y;
    }
    atomicAdd(&pooled[cur * HD + c], acc);
}

// ---------------- column stats over pooled [rows][128] ----------------
__global__ void k_colstats(const float* __restrict__ X, float* __restrict__ stats, int rows) {
    int c = threadIdx.x;  // 128
    float s = 0.f, q = 0.f;
    for (int r = blockIdx.x; r < rows; r += gridDim.x) {
        float v = X[r * HD + c];
        s += v; q += v * v;
    }
    int slot = (blockIdx.x & (NCOPY - 1)) * 256;
    atomicAdd(&stats[slot + c], s);
    atomicAdd(&stats[slot + 128 + c], q);
}

// ---------------- final: out[g] = bn2(pooled[g]) @ fcW + fcb ----------------
__global__ void k_final(const float* __restrict__ pooled, const float* __restrict__ bnp,
                        const float* __restrict__ fcW, const float* __restrict__ fcb,
                        float* __restrict__ outp, int G) {
    __shared__ float Wlds[HD * 64];
    __shared__ float prow[HD];
    int tid = threadIdx.x;  // 64
    for (int i = tid; i < HD * 64 / 4; i += 64) ((float4*)Wlds)[i] = ((const float4*)fcW)[i];
    int g = blockIdx.x;
    for (int c = tid; c < HD; c += 64) prow[c] = pooled[g * HD + c] * bnp[c] + bnp[128 + c];
    __syncthreads();
    float acc = fcb[tid];
#pragma unroll 8
    for (int c = 0; c < HD; ++c) acc += prow[c] * Wlds[c * 64 + tid];
    outp[g * 64 + tid] = acc;
}

// ---------------- host orchestration ----------------
extern "C" void kernel_launch(void* const* d_in, const int* in_sizes, int n_in,
                              void* d_out, int out_size, void* d_ws, size_t ws_size,
                              hipStream_t stream) {
    const float* x     = (const float*)d_in[0];
    const int*   ei    = (const int*)d_in[1];
    const int*   batch = (const int*)d_in[2];
    const float* Wl    = (const float*)d_in[3];
    const float* bl    = (const float*)d_in[4];
    const float* Wr    = (const float*)d_in[5];
    const float* bng   = (const float*)d_in[6];
    const float* bnb   = (const float*)d_in[7];
    const float* bn2g  = (const float*)d_in[8];
    const float* bn2b  = (const float*)d_in[9];
    const float* fcW   = (const float*)d_in[10];
    const float* fcb   = (const float*)d_in[11];

    int N = in_sizes[0] / HD;
    int E = in_sizes[1] / 2;
    int G = out_size / 64;
    const int* src = ei;
    const int* dst = ei + E;

    char* p = (char*)d_ws;
    auto alloc = [&](size_t bytes) -> void* {
        void* r = (void*)p;
        p += (bytes + 255) & ~(size_t)255;
        return r;
    };
    int NB = (N + BSZ - 1) >> BSH;   // buckets (<=512 for N<=131072)
    int nPB = (E + EPB - 1) / EPB;

    int*    rowptr   = (int*)alloc((size_t)(N + 1) * 4);
    int*    bCount   = (int*)alloc((size_t)NB * 4);
    int*    bBase    = (int*)alloc((size_t)(NB + 1) * 4);
    int*    gCursor  = (int*)alloc((size_t)NB * 4);
    int*    csr      = (int*)alloc((size_t)E * 4);
    float*  inv      = (float*)alloc((size_t)N * 4);
    ushort* WT       = (ushort*)alloc((size_t)3 * 128 * 256 * 2);
    ushort* xb       = (ushort*)alloc((size_t)N * HD * 2);
    ushort* aggb     = (ushort*)alloc((size_t)N * HD * 2);
    ushort* hb1      = (ushort*)alloc((size_t)N * HD * 2);
    ushort* hb2      = (ushort*)alloc((size_t)N * HD * 2);
    float*  statsAll = (float*)alloc((size_t)3 * NCOPY * 256 * 4);
    float*  stats2   = (float*)alloc((size_t)NCOPY * 256 * 4);
    float*  bnp      = (float*)alloc(256 * 4);
    float*  pooled   = (float*)alloc((size_t)G * HD * 4);

    float* stats0 = statsAll;
    float* stats1 = statsAll + NCOPY * 256;
    float* statsL2 = statsAll + 2 * NCOPY * 256;

    // packed edge list overlays aggb: dead before first k_agg writes aggb (stream-ordered)
    unsigned int* packed = (unsigned int*)aggb;

    float* outp = (float*)d_out;
    int total4 = N * HD / 4;
    int total8 = N * HD / 8;
    int ggrid = (N + 127) / 128;
    int agrid = (N + 3) / 4;

    // upfront zeroing (all atomic-accumulated buffers), then independent conversions
    hipMemsetAsync(statsAll, 0, (size_t)3 * NCOPY * 256 * 4, stream);
    hipMemsetAsync(stats2, 0, (size_t)NCOPY * 256 * 4, stream);
    hipMemsetAsync(pooled, 0, (size_t)G * HD * 4, stream);
    hipMemsetAsync(bCount, 0, (size_t)NB * 4, stream);
    k_cvt<<<2048, 256, 0, stream>>>(x, xb, total4);
    k_wt<<<(3 * 128 * 256 + 255) / 256, 256, 0, stream>>>(Wl, Wr, WT, 3 * 128 * 256);

    // bucketed CSR build
    kp_count<<<nPB, 256, 0, stream>>>(dst, bCount, E, NB);
    kp_scan<<<1, 512, 0, stream>>>(bCount, bBase, gCursor, NB, E);
    kp_part<<<nPB, 256, 0, stream>>>(src, dst, gCursor, packed, E, NB);
    kp_degscan<<<NB, 256, 0, stream>>>(packed, bBase, rowptr, inv, N, E);
    kp_fill<<<NB, 256, 0, stream>>>(packed, bBase, rowptr, csr, N);

    // layer 0: h=xb -> hb1
    k_agg<<<agrid, 256, 0, stream>>>(xb, rowptr, csr, inv, aggb, N);
    k_gemm<<<ggrid, 256, 0, stream>>>(aggb, xb, WT, bl, hb1, stats0, N);
    k_bnfin<<<1, 128, 0, stream>>>(stats0, bng, bnb, bnp, (float)N);
    k_apply<<<2048, 256, 0, stream>>>(hb1, bnp, total8);

    // layer 1: h=hb1 -> hb2
    k_agg<<<agrid, 256, 0, stream>>>(hb1, rowptr, csr, inv, aggb, N);
    k_gemm<<<ggrid, 256, 0, stream>>>(aggb, hb1, WT + 32768, bl + 128, hb2, stats1, N);
    k_bnfin<<<1, 128, 0, stream>>>(stats1, bng + 128, bnb + 128, bnp, (float)N);
    k_apply<<<2048, 256, 0, stream>>>(hb2, bnp, total8);

    // layer 2: h=hb2 -> hb1 (pre-BN); BN+leaky fused into pooling
    k_agg<<<agrid, 256, 0, stream>>>(hb2, rowptr, csr, inv, aggb, N);
    k_gemm<<<ggrid, 256, 0, stream>>>(aggb, hb2, WT + 65536, bl + 256, hb1, statsL2, N);
    k_bnfin<<<1, 128, 0, stream>>>(statsL2, bng + 256, bnb + 256, bnp, (float)N);
    k_poolapply<<<(N + 15) / 16, HD, 0, stream>>>(hb1, bnp, batch, pooled, N);

    // final BN + FC
    k_colstats<<<64, HD, 0, stream>>>(pooled, stats2, G);
    k_bnfin<<<1, 128, 0, stream>>>(stats2, bn2g, bn2b, bnp, (float)G);
    k_final<<<G, 64, 0, stream>>>(pooled, bnp, fcW, fcb, outp, G);
}

// Round 7
// 411.380 us; speedup vs baseline: 2.7781x; 1.0228x over previous
//
#include <hip/hip_runtime.h>

#define HD 128
#define NCOPY 32
#define BSH 8
#define BSZ 256
#define EPB 4096

typedef __attribute__((ext_vector_type(8))) short short8;
typedef __attribute__((ext_vector_type(4))) float f32x4;

union ABu { unsigned long long u[2]; short8 s8; };

__device__ inline float bf2f(ushort u) {
    union { unsigned int i; float f; } x; x.i = ((unsigned int)u) << 16; return x.f;
}
__device__ inline float bflo(unsigned int u) {
    union { unsigned int i; float f; } x; x.i = u << 16; return x.f;
}
__device__ inline float bfhi(unsigned int u) {
    union { unsigned int i; float f; } x; x.i = u & 0xffff0000u; return x.f;
}
__device__ inline ushort f2bf(float f) {
    union { float f; unsigned int i; } x; x.f = f;
    unsigned int r = x.i + 0x7FFF + ((x.i >> 16) & 1);
    return (ushort)(r >> 16);
}

// ---------------- Bucketed CSR build ----------------
// bucket = dst >> BSH (256 nodes / bucket). Packed edge word: src | (dst&255)<<17.

__global__ __launch_bounds__(256) void kp_count(const int* __restrict__ dst,
                                                int* __restrict__ bucketCount, int E, int NB) {
    __shared__ int hist[512];
    for (int i = threadIdx.x; i < NB; i += 256) hist[i] = 0;
    __syncthreads();
    int e0 = blockIdx.x * EPB;
#pragma unroll
    for (int j = 0; j < 16; ++j) {
        int e = e0 + j * 256 + threadIdx.x;
        if (e < E) atomicAdd(&hist[dst[e] >> BSH], 1);
    }
    __syncthreads();
    for (int i = threadIdx.x; i < NB; i += 256)
        if (hist[i]) atomicAdd(&bucketCount[i], hist[i]);
}

// single block, 512 threads: exclusive scan of bucketCount (NB <= 512)
__global__ void kp_scan(const int* __restrict__ bucketCount, int* __restrict__ bucketBase,
                        int* __restrict__ gCursor, int NB, int E) {
    __shared__ int lds[512];
    int tid = threadIdx.x;
    int v = (tid < NB) ? bucketCount[tid] : 0;
    lds[tid] = v;
    __syncthreads();
    for (int off = 1; off < 512; off <<= 1) {
        int t = 0;
        if (tid >= off) t = lds[tid - off];
        __syncthreads();
        if (tid >= off) lds[tid] += t;
        __syncthreads();
    }
    int excl = lds[tid] - v;
    if (tid < NB) { bucketBase[tid] = excl; gCursor[tid] = excl; }
    if (tid == 0) bucketBase[NB] = E;
}

__global__ __launch_bounds__(256) void kp_part(const int* __restrict__ src,
                                               const int* __restrict__ dst,
                                               int* __restrict__ gCursor,
                                               unsigned int* __restrict__ packed, int E, int NB) {
    __shared__ int hist[512], lbase[512], lcur[512];
    for (int i = threadIdx.x; i < NB; i += 256) hist[i] = 0;
    __syncthreads();
    int e0 = blockIdx.x * EPB;
    int b[16]; unsigned int w[16];
#pragma unroll
    for (int j = 0; j < 16; ++j) {
        int e = e0 + j * 256 + threadIdx.x;
        b[j] = -1;
        if (e < E) {
            int d = dst[e];
            int s = src[e];
            b[j] = d >> BSH;
            w[j] = (unsigned int)s | (((unsigned int)d & (BSZ - 1)) << 17);
            atomicAdd(&hist[b[j]], 1);
        }
    }
    __syncthreads();
    for (int i = threadIdx.x; i < NB; i += 256) {
        int c = hist[i];
        lbase[i] = c ? atomicAdd(&gCursor[i], c) : 0;
        lcur[i] = 0;
    }
    __syncthreads();
#pragma unroll
    for (int j = 0; j < 16; ++j) {
        if (b[j] >= 0) {
            int r = atomicAdd(&lcur[b[j]], 1);
            packed[lbase[b[j]] + r] = w[j];
        }
    }
}

// one block per bucket: degree count + intra-bucket scan -> rowptr/inv, then fill csr.
// Second pass over packed hits L2 (block's window ~16KB).
__global__ __launch_bounds__(256) void kp_degfill(const unsigned int* __restrict__ packed,
                                                  const int* __restrict__ bucketBase,
                                                  int* __restrict__ rowptr,
                                                  float* __restrict__ inv,
                                                  int* __restrict__ csr, int N, int E) {
    __shared__ int dcnt[BSZ];
    __shared__ int scn[BSZ];
    __shared__ int rp[BSZ];
    int bkt = blockIdx.x;
    int tid = threadIdx.x;
    int n0 = bkt << BSH;
    dcnt[tid] = 0;
    __syncthreads();
    int beg = bucketBase[bkt], end = bucketBase[bkt + 1];
    for (int e = beg + tid; e < end; e += 256)
        atomicAdd(&dcnt[packed[e] >> 17], 1);
    __syncthreads();
    int v = dcnt[tid];
    scn[tid] = v;
    __syncthreads();
    for (int off = 1; off < 256; off <<= 1) {
        int t = 0;
        if (tid >= off) t = scn[tid - off];
        __syncthreads();
        if (tid >= off) scn[tid] += t;
        __syncthreads();
    }
    int rpv = beg + scn[tid] - v;
    int n = n0 + tid;
    if (n < N) {
        rowptr[n] = rpv;
        inv[n] = (v > 0) ? (1.0f / (float)v) : 0.0f;
    }
    if (bkt == 0 && tid == 0) rowptr[N] = E;
    __syncthreads();
    dcnt[tid] = 0;       // reuse as cursor
    rp[tid] = rpv;
    __syncthreads();
    for (int e = beg + tid; e < end; e += 256) {
        unsigned int wv = packed[e];
        int ld = wv >> 17;
        int p = atomicAdd(&dcnt[ld], 1);
        csr[rp[ld] + p] = (int)(wv & 0x1FFFF);
    }
}

// ---------------- convert fp32 -> bf16 ----------------
__global__ void k_cvt(const float* __restrict__ in, ushort* __restrict__ out, int total4) {
    int i = blockIdx.x * blockDim.x + threadIdx.x;
    int stride = gridDim.x * blockDim.x;
    for (int idx = i; idx < total4; idx += stride) {
        float4 v = ((const float4*)in)[idx];
        ushort4 o;
        o.x = f2bf(v.x); o.y = f2bf(v.y); o.z = f2bf(v.z); o.w = f2bf(v.w);
        ((ushort4*)out)[idx] = o;
    }
}

// WT[l][col][k], k in 0..255 (k<128 -> Wl, else Wr), bf16
__global__ void k_wt(const float* __restrict__ Wl, const float* __restrict__ Wr,
                     ushort* __restrict__ WT, int total) {
    int i = blockIdx.x * blockDim.x + threadIdx.x;
    if (i >= total) return;
    int l = i >> 15;
    int rem = i & 32767;
    int col = rem >> 8;
    int k = rem & 255;
    float v = (k < 128) ? Wl[l * 16384 + k * 128 + col] : Wr[l * 16384 + (k - 128) * 128 + col];
    WT[i] = f2bf(v);
}

// ---------------- Aggregation: one wave per node, 8 rows in flight (R5-proven) ----------------
__global__ __launch_bounds__(256) void k_agg(const ushort* __restrict__ h,
                                             const int* __restrict__ rowptr,
                                             const int* __restrict__ csr,
                                             const float* __restrict__ inv,
                                             ushort* __restrict__ agg, int N) {
    int node = blockIdx.x * 4 + (threadIdx.x >> 6);
    if (node >= N) return;
    int lane = threadIdx.x & 63;
    int g = lane >> 4, ln = lane & 15;
    int beg = rowptr[node], end = rowptr[node + 1];
    float a[8], b[8];
#pragma unroll
    for (int j = 0; j < 8; ++j) { a[j] = 0.f; b[j] = 0.f; }
    for (int e = beg + g; e < end; e += 8) {
        int s0 = csr[e];
        uint4 v0 = *(const uint4*)&h[(size_t)s0 * HD + ln * 8];
        int e1 = e + 4;
        if (e1 < end) {
            int s1 = csr[e1];
            uint4 v1 = *(const uint4*)&h[(size_t)s1 * HD + ln * 8];
            b[0] += bflo(v1.x); b[1] += bfhi(v1.x);
            b[2] += bflo(v1.y); b[3] += bfhi(v1.y);
            b[4] += bflo(v1.z); b[5] += bfhi(v1.z);
            b[6] += bflo(v1.w); b[7] += bfhi(v1.w);
        }
        a[0] += bflo(v0.x); a[1] += bfhi(v0.x);
        a[2] += bflo(v0.y); a[3] += bfhi(v0.y);
        a[4] += bflo(v0.z); a[5] += bfhi(v0.z);
        a[6] += bflo(v0.w); a[7] += bfhi(v0.w);
    }
#pragma unroll
    for (int j = 0; j < 8; ++j) {
        a[j] += b[j];
        a[j] += __shfl_xor(a[j], 16);
        a[j] += __shfl_xor(a[j], 32);
    }
    if (lane < 16) {
        float iv = inv[node];
        ushort o[8];
#pragma unroll
        for (int j = 0; j < 8; ++j) o[j] = f2bf(a[j] * iv);
        *(uint4*)&agg[(size_t)node * HD + ln * 8] = *(uint4*)o;
    }
}

// ---------------- MFMA dual-GEMM, BK=64: out = [X1|X2](Nx256) @ WT^T(256x128) + bias ----
// 128x128 tile, 4 waves (2x2), 16x16x32 bf16 MFMA, K=256 in 4 chunks of 64.
// LDS row stride 72 ushorts (144B): 16B-aligned staging, 2-way banks on b64 frag reads (free).
__global__ __launch_bounds__(256) void k_gemm(
        const ushort* __restrict__ X1, const ushort* __restrict__ X2,
        const ushort* __restrict__ WT, const float* __restrict__ bias,
        ushort* __restrict__ out, float* __restrict__ stats, int N) {
    __shared__ ushort As[128 * 72];
    __shared__ ushort Bs[128 * 72];
    int tid = threadIdx.x;
    int lane = tid & 63, wid = tid >> 6;
    int wr = wid >> 1, wc = wid & 1;
    int ln15 = lane & 15, kg = lane >> 4;
    int rbase = blockIdx.x * 128;

    f32x4 acc[4][4];
#pragma unroll
    for (int m = 0; m < 4; ++m)
#pragma unroll
        for (int nn = 0; nn < 4; ++nn) acc[m][nn] = (f32x4){0.f, 0.f, 0.f, 0.f};

    for (int c = 0; c < 4; ++c) {
        const ushort* X = (c < 2) ? X1 : X2;
        int cb = (c & 1) * 64;
        // stage A tile [128 rows][64 k] (16KB): 4 x uint4 per thread
#pragma unroll
        for (int p = 0; p < 4; ++p) {
            int g = tid + p * 256;
            int r = g >> 3, q = g & 7;
            int grow = rbase + r;
            uint4 v = {0u, 0u, 0u, 0u};
            if (grow < N) v = *(const uint4*)&X[(size_t)grow * HD + cb + q * 8];
            *(uint4*)&As[r * 72 + q * 8] = v;
        }
        // stage B tile [128 cols][64 k]
#pragma unroll
        for (int p = 0; p < 4; ++p) {
            int g = tid + p * 256;
            int col = g >> 3, q = g & 7;
            *(uint4*)&Bs[col * 72 + q * 8] = *(const uint4*)&WT[col * 256 + c * 64 + q * 8];
        }
        __syncthreads();
#pragma unroll
        for (int kk = 0; kk < 2; ++kk) {
            short8 af[4], bfr[4];
#pragma unroll
            for (int m = 0; m < 4; ++m) {
                int row = wr * 64 + m * 16 + ln15;
                const ushort* pa = &As[row * 72 + kk * 32 + kg * 4];
                ABu u; u.u[0] = *(const unsigned long long*)pa;
                u.u[1] = *(const unsigned long long*)(pa + 16);
                af[m] = u.s8;
            }
#pragma unroll
            for (int nn = 0; nn < 4; ++nn) {
                int col = wc * 64 + nn * 16 + ln15;
                const ushort* pb = &Bs[col * 72 + kk * 32 + kg * 4];
                ABu u; u.u[0] = *(const unsigned long long*)pb;
                u.u[1] = *(const unsigned long long*)(pb + 16);
                bfr[nn] = u.s8;
            }
#pragma unroll
            for (int m = 0; m < 4; ++m)
#pragma unroll
                for (int nn = 0; nn < 4; ++nn)
                    acc[m][nn] = __builtin_amdgcn_mfma_f32_16x16x32_bf16(af[m], bfr[nn], acc[m][nn], 0, 0, 0);
        }
        __syncthreads();
    }

    float s[4] = {0.f, 0.f, 0.f, 0.f};
    float q[4] = {0.f, 0.f, 0.f, 0.f};
    float bv[4];
#pragma unroll
    for (int nn = 0; nn < 4; ++nn) bv[nn] = bias[wc * 64 + nn * 16 + ln15];
#pragma unroll
    for (int m = 0; m < 4; ++m) {
#pragma unroll
        for (int j = 0; j < 4; ++j) {
            int row = rbase + wr * 64 + m * 16 + kg * 4 + j;
            if (row < N) {
#pragma unroll
                for (int nn = 0; nn < 4; ++nn) {
                    float v = acc[m][nn][j] + bv[nn];
                    out[(size_t)row * HD + wc * 64 + nn * 16 + ln15] = f2bf(v);
                    s[nn] += v; q[nn] += v * v;
                }
            }
        }
    }
#pragma unroll
    for (int nn = 0; nn < 4; ++nn) {
        s[nn] += __shfl_xor(s[nn], 16); s[nn] += __shfl_xor(s[nn], 32);
        q[nn] += __shfl_xor(q[nn], 16); q[nn] += __shfl_xor(q[nn], 32);
    }
    if (lane < 16) {
        int slot = (blockIdx.x & (NCOPY - 1)) * 256;
#pragma unroll
        for (int nn = 0; nn < 4; ++nn) {
            int col = wc * 64 + nn * 16 + lane;
            atomicAdd(&stats[slot + col], s[nn]);
            atomicAdd(&stats[slot + 128 + col], q[nn]);
        }
    }
}

// ---------------- BN finalize ----------------
__global__ void k_bnfin(const float* __restrict__ stats, const float* __restrict__ gamma,
                        const float* __restrict__ beta, float* __restrict__ bnp, float count) {
    int c = threadIdx.x;  // 128
    float s = 0.f, q = 0.f;
    for (int i = 0; i < NCOPY; ++i) { s += stats[i * 256 + c]; q += stats[i * 256 + 128 + c]; }
    float mean = s / count;
    float var = q / count - mean * mean;
    var = fmaxf(var, 0.f);
    float scale = gamma[c] * rsqrtf(var + 1e-5f);
    bnp[c] = scale;
    bnp[128 + c] = beta[c] - mean * scale;
}

// ---------------- BN apply + LeakyReLU, IN-PLACE on bf16 buffer ----------------
__global__ void k_apply(ushort* buf, const float* __restrict__ bnp, int total8) {
    int i = blockIdx.x * blockDim.x + threadIdx.x;
    int stride = gridDim.x * blockDim.x;
    for (int idx = i; idx < total8; idx += stride) {
        int cb = (idx * 8) & (HD - 1);
        uint4 v = ((const uint4*)buf)[idx];
        float f[8];
        f[0] = bflo(v.x); f[1] = bfhi(v.x);
        f[2] = bflo(v.y); f[3] = bfhi(v.y);
        f[4] = bflo(v.z); f[5] = bfhi(v.z);
        f[6] = bflo(v.w); f[7] = bfhi(v.w);
        ushort o[8];
#pragma unroll
        for (int j = 0; j < 8; ++j) {
            float y = f[j] * bnp[cb + j] + bnp[128 + cb + j];
            y = (y > 0.f) ? y : 0.2f * y;
            o[j] = f2bf(y);
        }
        ((uint4*)buf)[idx] = *(uint4*)o;
    }
}

// ---------------- Pooling with fused BN+LeakyReLU (batch sorted, h = pre-BN bf16) --------
__global__ void k_poolapply(const ushort* __restrict__ h, const float* __restrict__ bnp,
                            const int* __restrict__ batch, float* __restrict__ pooled, int N) {
    int c = threadIdx.x;  // 128
    float sc = bnp[c], sh = bnp[128 + c];
    int n0 = blockIdx.x * 16;
    if (n0 >= N) return;
    int nend = min(n0 + 16, N);
    float acc = 0.f;
    int cur = batch[n0];
    for (int n = n0; n < nend; ++n) {
        int b = batch[n];
        if (b != cur) { atomicAdd(&pooled[cur * HD + c], acc); acc = 0.f; cur = b; }
        float y = bf2f(h[(size_t)n * HD + c]) * sc + sh;
        y = (y > 0.f) ? y : 0.2f * y;
        acc += y;
    }
    atomicAdd(&pooled[cur * HD + c], acc);
}

// ---------------- column stats over pooled [rows][128] ----------------
__global__ void k_colstats(const float* __restrict__ X, float* __restrict__ stats, int rows) {
    int c = threadIdx.x;  // 128
    float s = 0.f, q = 0.f;
    for (int r = blockIdx.x; r < rows; r += gridDim.x) {
        float v = X[r * HD + c];
        s += v; q += v * v;
    }
    int slot = (blockIdx.x & (NCOPY - 1)) * 256;
    atomicAdd(&stats[slot + c], s);
    atomicAdd(&stats[slot + 128 + c], q);
}

// ---------------- final: out[g] = bn2(pooled[g]) @ fcW + fcb ----------------
__global__ void k_final(const float* __restrict__ pooled, const float* __restrict__ bnp,
                        const float* __restrict__ fcW, const float* __restrict__ fcb,
                        float* __restrict__ outp, int G) {
    __shared__ float Wlds[HD * 64];
    __shared__ float prow[HD];
    int tid = threadIdx.x;  // 64
    for (int i = tid; i < HD * 64 / 4; i += 64) ((float4*)Wlds)[i] = ((const float4*)fcW)[i];
    int g = blockIdx.x;
    for (int c = tid; c < HD; c += 64) prow[c] = pooled[g * HD + c] * bnp[c] + bnp[128 + c];
    __syncthreads();
    float acc = fcb[tid];
#pragma unroll 8
    for (int c = 0; c < HD; ++c) acc += prow[c] * Wlds[c * 64 + tid];
    outp[g * 64 + tid] = acc;
}

// ---------------- host orchestration ----------------
extern "C" void kernel_launch(void* const* d_in, const int* in_sizes, int n_in,
                              void* d_out, int out_size, void* d_ws, size_t ws_size,
                              hipStream_t stream) {
    const float* x     = (const float*)d_in[0];
    const int*   ei    = (const int*)d_in[1];
    const int*   batch = (const int*)d_in[2];
    const float* Wl    = (const float*)d_in[3];
    const float* bl    = (const float*)d_in[4];
    const float* Wr    = (const float*)d_in[5];
    const float* bng   = (const float*)d_in[6];
    const float* bnb   = (const float*)d_in[7];
    const float* bn2g  = (const float*)d_in[8];
    const float* bn2b  = (const float*)d_in[9];
    const float* fcW   = (const float*)d_in[10];
    const float* fcb   = (const float*)d_in[11];

    int N = in_sizes[0] / HD;
    int E = in_sizes[1] / 2;
    int G = out_size / 64;
    const int* src = ei;
    const int* dst = ei + E;

    char* p = (char*)d_ws;
    auto alloc = [&](size_t bytes) -> void* {
        void* r = (void*)p;
        p += (bytes + 255) & ~(size_t)255;
        return r;
    };
    int NB = (N + BSZ - 1) >> BSH;   // buckets (<=512 for N<=131072)
    int nPB = (E + EPB - 1) / EPB;

    int*    rowptr   = (int*)alloc((size_t)(N + 1) * 4);
    int*    bCount   = (int*)alloc((size_t)NB * 4);
    int*    bBase    = (int*)alloc((size_t)(NB + 1) * 4);
    int*    gCursor  = (int*)alloc((size_t)NB * 4);
    int*    csr      = (int*)alloc((size_t)E * 4);
    float*  inv      = (float*)alloc((size_t)N * 4);
    ushort* WT       = (ushort*)alloc((size_t)3 * 128 * 256 * 2);
    ushort* xb       = (ushort*)alloc((size_t)N * HD * 2);
    ushort* aggb     = (ushort*)alloc((size_t)N * HD * 2);
    ushort* hb1      = (ushort*)alloc((size_t)N * HD * 2);
    ushort* hb2      = (ushort*)alloc((size_t)N * HD * 2);
    float*  statsAll = (float*)alloc((size_t)3 * NCOPY * 256 * 4);
    float*  stats2   = (float*)alloc((size_t)NCOPY * 256 * 4);
    float*  bnp      = (float*)alloc(256 * 4);
    float*  pooled   = (float*)alloc((size_t)G * HD * 4);

    float* stats0 = statsAll;
    float* stats1 = statsAll + NCOPY * 256;
    float* statsL2 = statsAll + 2 * NCOPY * 256;

    // packed edge list overlays aggb: dead before first k_agg writes aggb (stream-ordered)
    unsigned int* packed = (unsigned int*)aggb;

    float* outp = (float*)d_out;
    int total4 = N * HD / 4;
    int total8 = N * HD / 8;
    int ggrid = (N + 127) / 128;
    int agrid = (N + 3) / 4;

    // upfront zeroing (all atomic-accumulated buffers), then independent conversions
    hipMemsetAsync(statsAll, 0, (size_t)3 * NCOPY * 256 * 4, stream);
    hipMemsetAsync(stats2, 0, (size_t)NCOPY * 256 * 4, stream);
    hipMemsetAsync(pooled, 0, (size_t)G * HD * 4, stream);
    hipMemsetAsync(bCount, 0, (size_t)NB * 4, stream);
    k_cvt<<<2048, 256, 0, stream>>>(x, xb, total4);
    k_wt<<<(3 * 128 * 256 + 255) / 256, 256, 0, stream>>>(Wl, Wr, WT, 3 * 128 * 256);

    // bucketed CSR build
    kp_count<<<nPB, 256, 0, stream>>>(dst, bCount, E, NB);
    kp_scan<<<1, 512, 0, stream>>>(bCount, bBase, gCursor, NB, E);
    kp_part<<<nPB, 256, 0, stream>>>(src, dst, gCursor, packed, E, NB);
    kp_degfill<<<NB, 256, 0, stream>>>(packed, bBase, rowptr, inv, csr, N, E);

    // layer 0: h=xb -> hb1
    k_agg<<<agrid, 256, 0, stream>>>(xb, rowptr, csr, inv, aggb, N);
    k_gemm<<<ggrid, 256, 0, stream>>>(aggb, xb, WT, bl, hb1, stats0, N);
    k_bnfin<<<1, 128, 0, stream>>>(stats0, bng, bnb, bnp, (float)N);
    k_apply<<<2048, 256, 0, stream>>>(hb1, bnp, total8);

    // layer 1: h=hb1 -> hb2
    k_agg<<<agrid, 256, 0, stream>>>(hb1, rowptr, csr, inv, aggb, N);
    k_gemm<<<ggrid, 256, 0, stream>>>(aggb, hb1, WT + 32768, bl + 128, hb2, stats1, N);
    k_bnfin<<<1, 128, 0, stream>>>(stats1, bng + 128, bnb + 128, bnp, (float)N);
    k_apply<<<2048, 256, 0, stream>>>(hb2, bnp, total8);

    // layer 2: h=hb2 -> hb1 (pre-BN); BN+leaky fused into pooling
    k_agg<<<agrid, 256, 0, stream>>>(hb2, rowptr, csr, inv, aggb, N);
    k_gemm<<<ggrid, 256, 0, stream>>>(aggb, hb2, WT + 65536, bl + 256, hb1, statsL2, N);
    k_bnfin<<<1, 128, 0, stream>>>(statsL2, bng + 256, bnb + 256, bnp, (float)N);
    k_poolapply<<<(N + 15) / 16, HD, 0, stream>>>(hb1, bnp, batch, pooled, N);

    // final BN + FC
    k_colstats<<<64, HD, 0, stream>>>(pooled, stats2, G);
    k_bnfin<<<1, 128, 0, stream>>>(stats2, bn2g, bn2b, bnp, (float)G);
    k_final<<<G, 64, 0, stream>>>(pooled, bnp, fcW, fcb, outp, G);
}